// Round 8
// baseline (201.838 us; speedup 1.0000x reference)
//
#include <hip/hip_runtime.h>

// MaskedAttentionLayer B=4,S=2048,E=1024,H=16,HD=64; fp32 io, bf16 MFMA.
// R14: flash_attn unit body restructured: K and V LDS fragments are loaded
// ONCE per (kt,h2) and shared by both paired q-tiles (they are identical;
// only qf/pf differ) -> 32 ds_read_b128 per unit drops to 16. Kernel was
// LDS-read-throughput saturated (R13 analysis: ~148K LDS cycles/CU vs 143K
// dispatch). Inactive small-tile units use pf1=0 (exact zero-adds, outputs
// bit-identical; wave-uniform guard skips its exp2/Ps VALU work).
// Staging, sync skeleton, swizzles, grid 512x512thr unchanged from R13.
// qkv_gemm (R12 128^2) + cvt_all unchanged.

typedef __bf16 bf16x8 __attribute__((ext_vector_type(8)));
typedef __bf16 bf16x4 __attribute__((ext_vector_type(4)));
typedef float f32x4 __attribute__((ext_vector_type(4)));
typedef unsigned short us8 __attribute__((ext_vector_type(8)));
typedef unsigned short us4 __attribute__((ext_vector_type(4)));

#define Bb 4
#define Ss 2048
#define Ee 1024
#define Hh 16
#define HD 64

#if __has_builtin(__builtin_amdgcn_exp2f)
#define EXP2(x) __builtin_amdgcn_exp2f(x)
#else
#define EXP2(x) exp2f(x)
#endif

__device__ __forceinline__ unsigned short f2bf(float f) {
  union { float f; unsigned u; } v; v.f = f;
  unsigned u = v.u;
  u += 0x7fffu + ((u >> 16) & 1u);   // RNE
  return (unsigned short)(u >> 16);
}

__device__ __forceinline__ void gl_lds16(const void* g, void* l) {
  __builtin_amdgcn_global_load_lds((const __attribute__((address_space(1))) void*)g,
                                   (__attribute__((address_space(3))) void*)l, 16, 0, 0);
}

// ds_read_b128 with compile-time byte offset; opaque to compiler waitcnt logic.
#define DSR(d, a, o) asm volatile("ds_read_b128 %0, %1 offset:" #o : "=v"(d) : "v"(a))

// one kernel for all fp32->bf16 converts (x, Wq, Wk, Wv)
__global__ __launch_bounds__(256) void cvt_all(const float* __restrict__ x,
                                               const float* __restrict__ wq,
                                               const float* __restrict__ wk,
                                               const float* __restrict__ wv,
                                               unsigned short* __restrict__ xb,
                                               unsigned short* __restrict__ wb) {
  int i = blockIdx.x * 256 + threadIdx.x;   // float4 index, total 2883584
  const float* src; unsigned short* dst; int idx;
  if (i < 2097152)      { src = x;  dst = xb;                idx = i; }
  else if (i < 2359296) { src = wq; dst = wb;                idx = i - 2097152; }
  else if (i < 2621440) { src = wk; dst = wb + 1048576;      idx = i - 2359296; }
  else                  { src = wv; dst = wb + 2 * 1048576;  idx = i - 2621440; }
  float4 f = ((const float4*)src)[idx];
  us4 o = { f2bf(f.x), f2bf(f.y), f2bf(f.z), f2bf(f.w) };
  ((us4*)dst)[idx] = o;
}

// C[m,n] = sum_e X[m,e] W[n,e] + bias[n].  (R12 structure, verified)
// 128x128 tile, BK=64, 256 threads = 4 waves, dispersed-quadrant map.
// Grid (64,8,3) = 1536 blocks, 2 blocks/CU, 3 exact rounds.
// z=0 (Q): [b,h,s,d] scaled by 0.125*log2e.  z=1 (K): [b,h,s,d].  z=2 (V): [b,h,d,s].
__global__ __launch_bounds__(256, 2) void qkv_gemm(const unsigned short* __restrict__ xb,
                                                   const unsigned short* __restrict__ wb_all,
                                                   const float* __restrict__ bq,
                                                   const float* __restrict__ bk,
                                                   const float* __restrict__ bv,
                                                   unsigned short* __restrict__ qkv) {
  const int z = blockIdx.z;
  const unsigned short* wb = wb_all + (size_t)z * (Ee * Ee);
  const float* bias = (z == 0) ? bq : (z == 1) ? bk : bv;
  unsigned short* outb = qkv + (size_t)z * (Bb * Ss * Ee);
  const float osc = (z == 0) ? 0.180336880f : 1.0f;   // 0.125 * log2(e)

  __shared__ unsigned short SMEM[32768];   // 64 KiB: 2 x (A 8192 + B 8192 elems)

  const int t = threadIdx.x;
  const int wave = t >> 6, lane = t & 63, quad = lane >> 4, ln = lane & 15;
  const int wr = wave >> 1, wc = wave & 1;
  const int m0 = blockIdx.x * 128, n0 = blockIdx.y * 128;

  const int r32 = t >> 3;
  const int cs = ((t & 7) ^ (r32 & 7)) * 8;
  const int t8 = t * 8;
  const unsigned short* gA0 = xb + (size_t)(m0 + r32) * Ee + cs;       // A rows 0..63
  const unsigned short* gA1 = gA0 + 64 * Ee;                           // A rows 64..127
  const unsigned short* gB0 = wb + (size_t)(n0 + r32) * Ee + cs;       // B rows 0..63
  const unsigned short* gB1 = gB0 + 64 * Ee;                           // B rows 64..127

  const int swz0 = ((0 * 4 + quad) ^ (ln & 7)) * 16;
  const int swz1 = ((1 * 4 + quad) ^ (ln & 7)) * 16;
  int aA0 = (wr * 32 + ln) * 128 + swz0;
  int aA1 = (wr * 32 + ln) * 128 + swz1;
  int bA0 = 16384 + (wc * 32 + ln) * 128 + swz0;
  int bA1 = 16384 + (wc * 32 + ln) * 128 + swz1;

  f32x4 acc[2][2][2][2] = {};
  bf16x8 af[2][2], bf0[2][2], bf1[2][2];

  // ---- prologue: stage tile 0 into buf0, half order A0,B0,B1,A1 (vmcnt order!)
  gl_lds16(gA0,           &SMEM[t8]);
  gl_lds16(gA0 + 32 * Ee, &SMEM[t8 + 2048]);
  gl_lds16(gB0,           &SMEM[8192 + t8]);
  gl_lds16(gB0 + 32 * Ee, &SMEM[8192 + t8 + 2048]);
  gl_lds16(gB1,           &SMEM[12288 + t8]);
  gl_lds16(gB1 + 32 * Ee, &SMEM[12288 + t8 + 2048]);
  gl_lds16(gA1,           &SMEM[4096 + t8]);
  gl_lds16(gA1 + 32 * Ee, &SMEM[4096 + t8 + 2048]);

#pragma unroll 1
  for (int kt = 0; kt < 15; ++kt) {
    const int sbuf = ((kt & 1) << 14) ^ 16384;   // stage buffer (elems) for tile kt+1
    const int co = (kt + 1) * 64;                // next tile's K-column offset

    // ================ phase 0: C(qa0,qb0); reads A-lo + B-lo; stages A0(kt+1)
    asm volatile("s_waitcnt vmcnt(4)" ::: "memory");
    asm volatile("s_barrier" ::: "memory");
    DSR(af[0][0], aA0, 0);    DSR(af[1][0], aA0, 2048);
    DSR(af[0][1], aA1, 0);    DSR(af[1][1], aA1, 2048);
    DSR(bf0[0][0], bA0, 0);   DSR(bf0[1][0], bA0, 2048);
    DSR(bf0[0][1], bA1, 0);   DSR(bf0[1][1], bA1, 2048);
    gl_lds16(gA0 + co,           &SMEM[sbuf + t8]);
    gl_lds16(gA0 + co + 32 * Ee, &SMEM[sbuf + t8 + 2048]);
    asm volatile("s_barrier" ::: "memory");
    asm volatile("s_waitcnt lgkmcnt(0)" ::: "memory");
    __builtin_amdgcn_sched_barrier(0);
    __builtin_amdgcn_s_setprio(1);
#pragma unroll
    for (int kk = 0; kk < 2; ++kk)
#pragma unroll
      for (int i = 0; i < 2; ++i)
#pragma unroll
        for (int j = 0; j < 2; ++j)
          acc[0][0][i][j] = __builtin_amdgcn_mfma_f32_16x16x32_bf16(af[i][kk], bf0[j][kk], acc[0][0][i][j], 0, 0, 0);
    __builtin_amdgcn_s_setprio(0);
    __builtin_amdgcn_sched_barrier(0);

    // ================ phase 1: C(qa0,qb1); reads B-hi; stages B0(kt+1)
    asm volatile("s_waitcnt vmcnt(4)" ::: "memory");
    asm volatile("s_barrier" ::: "memory");
    DSR(bf1[0][0], bA0, 8192); DSR(bf1[1][0], bA0, 10240);
    DSR(bf1[0][1], bA1, 8192); DSR(bf1[1][1], bA1, 10240);
    gl_lds16(gB0 + co,           &SMEM[sbuf + 8192 + t8]);
    gl_lds16(gB0 + co + 32 * Ee, &SMEM[sbuf + 8192 + t8 + 2048]);
    asm volatile("s_barrier" ::: "memory");
    asm volatile("s_waitcnt lgkmcnt(0)" ::: "memory");
    __builtin_amdgcn_sched_barrier(0);
    __builtin_amdgcn_s_setprio(1);
#pragma unroll
    for (int kk = 0; kk < 2; ++kk)
#pragma unroll
      for (int i = 0; i < 2; ++i)
#pragma unroll
        for (int j = 0; j < 2; ++j)
          acc[0][1][i][j] = __builtin_amdgcn_mfma_f32_16x16x32_bf16(af[i][kk], bf1[j][kk], acc[0][1][i][j], 0, 0, 0);
    __builtin_amdgcn_s_setprio(0);
    __builtin_amdgcn_sched_barrier(0);

    // ================ phase 2: C(qa1,qb0); reads A-hi; stages B1(kt+1)
    asm volatile("s_waitcnt vmcnt(4)" ::: "memory");
    asm volatile("s_barrier" ::: "memory");
    DSR(af[0][0], aA0, 8192); DSR(af[1][0], aA0, 10240);
    DSR(af[0][1], aA1, 8192); DSR(af[1][1], aA1, 10240);
    gl_lds16(gB1 + co,           &SMEM[sbuf + 12288 + t8]);
    gl_lds16(gB1 + co + 32 * Ee, &SMEM[sbuf + 12288 + t8 + 2048]);
    asm volatile("s_barrier" ::: "memory");
    asm volatile("s_waitcnt lgkmcnt(0)" ::: "memory");
    __builtin_amdgcn_sched_barrier(0);
    __builtin_amdgcn_s_setprio(1);
#pragma unroll
    for (int kk = 0; kk < 2; ++kk)
#pragma unroll
      for (int i = 0; i < 2; ++i)
#pragma unroll
        for (int j = 0; j < 2; ++j)
          acc[1][0][i][j] = __builtin_amdgcn_mfma_f32_16x16x32_bf16(af[i][kk], bf0[j][kk], acc[1][0][i][j], 0, 0, 0);
    __builtin_amdgcn_s_setprio(0);
    __builtin_amdgcn_sched_barrier(0);

    // ================ phase 3: C(qa1,qb1); no reads; stages A1(kt+1)
    asm volatile("s_barrier" ::: "memory");
    gl_lds16(gA1 + co,           &SMEM[sbuf + 4096 + t8]);
    gl_lds16(gA1 + co + 32 * Ee, &SMEM[sbuf + 4096 + t8 + 2048]);
    asm volatile("s_barrier" ::: "memory");
    __builtin_amdgcn_sched_barrier(0);
    __builtin_amdgcn_s_setprio(1);
#pragma unroll
    for (int kk = 0; kk < 2; ++kk)
#pragma unroll
      for (int i = 0; i < 2; ++i)
#pragma unroll
        for (int j = 0; j < 2; ++j)
          acc[1][1][i][j] = __builtin_amdgcn_mfma_f32_16x16x32_bf16(af[i][kk], bf1[j][kk], acc[1][1][i][j], 0, 0, 0);
    __builtin_amdgcn_s_setprio(0);
    __builtin_amdgcn_sched_barrier(0);

    aA0 ^= 32768; aA1 ^= 32768; bA0 ^= 32768; bA1 ^= 32768;
  }

  // ---- peeled tile 15: only place vmcnt drains to 0 (bases now at buf1)
  {
    asm volatile("s_waitcnt vmcnt(0)" ::: "memory");
    asm volatile("s_barrier" ::: "memory");
    DSR(af[0][0], aA0, 0);    DSR(af[1][0], aA0, 2048);
    DSR(af[0][1], aA1, 0);    DSR(af[1][1], aA1, 2048);
    DSR(bf0[0][0], bA0, 0);   DSR(bf0[1][0], bA0, 2048);
    DSR(bf0[0][1], bA1, 0);   DSR(bf0[1][1], bA1, 2048);
    DSR(bf1[0][0], bA0, 8192); DSR(bf1[1][0], bA0, 10240);
    DSR(bf1[0][1], bA1, 8192); DSR(bf1[1][1], bA1, 10240);
    asm volatile("s_waitcnt lgkmcnt(0)" ::: "memory");
    __builtin_amdgcn_sched_barrier(0);
#pragma unroll
    for (int kk = 0; kk < 2; ++kk)
#pragma unroll
      for (int i = 0; i < 2; ++i)
#pragma unroll
        for (int j = 0; j < 2; ++j) {
          acc[0][0][i][j] = __builtin_amdgcn_mfma_f32_16x16x32_bf16(af[i][kk], bf0[j][kk], acc[0][0][i][j], 0, 0, 0);
          acc[0][1][i][j] = __builtin_amdgcn_mfma_f32_16x16x32_bf16(af[i][kk], bf1[j][kk], acc[0][1][i][j], 0, 0, 0);
        }
    __builtin_amdgcn_sched_barrier(0);
    DSR(af[0][0], aA0, 8192); DSR(af[1][0], aA0, 10240);
    DSR(af[0][1], aA1, 8192); DSR(af[1][1], aA1, 10240);
    asm volatile("s_waitcnt lgkmcnt(0)" ::: "memory");
    __builtin_amdgcn_sched_barrier(0);
#pragma unroll
    for (int kk = 0; kk < 2; ++kk)
#pragma unroll
      for (int i = 0; i < 2; ++i)
#pragma unroll
        for (int j = 0; j < 2; ++j) {
          acc[1][0][i][j] = __builtin_amdgcn_mfma_f32_16x16x32_bf16(af[i][kk], bf0[j][kk], acc[1][0][i][j], 0, 0, 0);
          acc[1][1][i][j] = __builtin_amdgcn_mfma_f32_16x16x32_bf16(af[i][kk], bf1[j][kk], acc[1][1][i][j], 0, 0, 0);
        }
    __builtin_amdgcn_sched_barrier(0);
  }

  // ---- epilogue
  float biasj[2][2];
#pragma unroll
  for (int qb = 0; qb < 2; ++qb)
#pragma unroll
    for (int j = 0; j < 2; ++j)
      biasj[qb][j] = bias[n0 + qb * 64 + wc * 32 + j * 16 + ln];

  if (z != 2) {
#pragma unroll
    for (int qa = 0; qa < 2; ++qa)
#pragma unroll
      for (int qb = 0; qb < 2; ++qb)
#pragma unroll
        for (int i = 0; i < 2; ++i)
#pragma unroll
          for (int j = 0; j < 2; ++j)
#pragma unroll
            for (int r = 0; r < 4; ++r) {
              int m = m0 + qa * 64 + wr * 32 + i * 16 + quad * 4 + r;
              int n = n0 + qb * 64 + wc * 32 + j * 16 + ln;
              int b_ = m >> 11, s = m & 2047;
              int h = n >> 6, d = n & 63;
              outb[(((size_t)b_ * Hh + h) * Ss + s) * HD + d] =
                  f2bf((acc[qa][qb][i][j][r] + biasj[qb][j]) * osc);
            }
  } else {
    // V: transpose to [b,h,d,s] through LDS (128x128 fits in one pass)
    __syncthreads();
#pragma unroll
    for (int qa = 0; qa < 2; ++qa)
#pragma unroll
      for (int qb = 0; qb < 2; ++qb)
#pragma unroll
        for (int i = 0; i < 2; ++i)
#pragma unroll
          for (int j = 0; j < 2; ++j)
#pragma unroll
            for (int r = 0; r < 4; ++r) {
              int nc = qb * 64 + wc * 32 + j * 16 + ln;
              int mr = qa * 64 + wr * 32 + i * 16 + quad * 4 + r;
              SMEM[nc * 136 + mr] = f2bf(acc[qa][qb][i][j][r] + biasj[qb][j]);
            }
    __syncthreads();
    int nr = t >> 1, mh = t & 1;
    int n = n0 + nr, h = n >> 6, d = n & 63;
    int b_ = m0 >> 11;
    int s0 = (m0 & 2047) + mh * 64;
#pragma unroll
    for (int q = 0; q < 8; ++q) {
      us8 vdat = *(const us8*)&SMEM[nr * 136 + mh * 64 + q * 8];
      *(us8*)&outb[(((size_t)b_ * Hh + h) * HD + d) * Ss + s0 + q * 8] = vdat;
    }
  }
}

// Flash attention, causal, S^T = K Q^T, max-free exp2 softmax.
// R14: grid 512 (64 bh x 8 p); 512 thr / 8 waves. Block p computes BOTH
// q-tiles {15-p, p}; wave w owns 16-row strip w*16 of each. Per (kt,h2)
// unit: kf/vf fragments loaded ONCE and shared by both q-tiles; small
// q-tile's softmax guarded (wave-uniform), pf1=0 when inactive (zero-adds,
// bit-identical outputs). __syncthreads; 4x gl_lds16; __syncthreads.
__global__ __launch_bounds__(512, 2) void flash_attn(const unsigned short* __restrict__ qkv,
                                                     float* __restrict__ out) {
  const int id = blockIdx.x;
  const int bh = id & 63;
  const int p = id >> 6;            // 0..7
  const int b_ = bh >> 4, h = bh & 15;

  const unsigned short* qb  = qkv + (size_t)bh * (Ss * HD);
  const unsigned short* kb  = qkv + (size_t)(64 + bh) * (Ss * HD);
  const unsigned short* vtb = qkv + (size_t)(128 + bh) * (Ss * HD);  // [d][s]

  __shared__ __bf16 Ks[8192];          // [128 kcol][64 d], chunk swizzle c^(row&7)
  __shared__ __bf16 Vt[8192];          // [64 d][128 kk],  chunk swizzle c^(row&7)
  __shared__ __bf16 Ps[8][16][72];     // per-wave P scratch [qrow][kk]

  const int t = threadIdx.x;
  const int wave = t >> 6, lane = t & 63, quad = lane >> 4, ln = lane & 15;
  const int uw = wave >> 2;            // 64-row subtile half within each q-tile

  // staging (512 thr): K rows rk (+64 2nd call), 8 chunks/row;
  // V rows rv (+32 2nd call), 16 chunks/row.
  const int rk = t >> 3;               // 0..63
  const int ck = ((t & 7) ^ (rk & 7)) * 8;
  const int rv = t >> 4;               // 0..31
  const int cv = ((t & 15) ^ (rv & 7)) * 8;
  const int t8 = t * 8;

  const int qts[2] = { 15 - p, p };    // big triangle first; small reuses staging
  const int KTB = qts[0] + 1;          // 128-col blocks to stage
  const int su0 = 2 * qts[0] + uw;     // this wave's subtile index, big q-tile
  const int su1 = 2 * qts[1] + uw;     // ... small q-tile (su1 <= su0)
  const int qrow0 = qts[0] * 128 + wave * 16 + ln;
  const int qrow1 = qts[1] * 128 + wave * 16 + ln;

  bf16x8 qf[2][2];                     // [qt][ks]
#pragma unroll
  for (int qt = 0; qt < 2; ++qt)
#pragma unroll
    for (int ks = 0; ks < 2; ++ks)
      qf[qt][ks] = *(const bf16x8*)(qb + (size_t)(qts[qt] * 128 + wave * 16 + ln) * HD +
                                    ks * 32 + quad * 8);

  bf16x8 onef;
#pragma unroll
  for (int j = 0; j < 8; ++j) onef[j] = (__bf16)1.0f;

  f32x4 o[2][4] = {};                  // [qt][g]
  f32x4 l4[2] = {};                    // [qt]

#pragma unroll 1
  for (int kt = 0; kt < KTB; ++kt) {
    const unsigned short* kbt = kb + (size_t)kt * (128 * HD);
    const unsigned short* vbt = vtb + kt * 128;
    __syncthreads();
    gl_lds16(kbt + rk * HD + ck,        &Ks[t8]);
    gl_lds16(kbt + (rk + 64) * HD + ck, &Ks[t8 + 4096]);
    gl_lds16(vbt + rv * Ss + cv,        &Vt[t8]);
    gl_lds16(vbt + (rv + 32) * Ss + cv, &Vt[t8 + 4096]);
    __syncthreads();

#pragma unroll
    for (int h2 = 0; h2 < 2; ++h2) {
      const int kb64 = kt * 2 + h2;
      if (kb64 > su0) continue;                  // uniform; implies qt1 masked too
      const bool a1 = (kb64 <= su1);             // small q-tile active

      // S^T = K Q^T for BOTH q-tiles; each kf loaded once
      f32x4 s0[4] = {}, s1[4] = {};
#pragma unroll
      for (int g = 0; g < 4; ++g)
#pragma unroll
        for (int ks = 0; ks < 2; ++ks) {
          bf16x8 kf = *(const bf16x8*)&Ks[(h2 * 64 + g * 16 + ln) * 64 +
                                          (((ks * 4 + quad) ^ (ln & 7)) * 8)];
          s0[g] = __builtin_amdgcn_mfma_f32_16x16x32_bf16(kf, qf[0][ks], s0[g], 0, 0, 0);
          s1[g] = __builtin_amdgcn_mfma_f32_16x16x32_bf16(kf, qf[1][ks], s1[g], 0, 0, 0);
        }

      const int k0 = kb64 * 64;
      if (kb64 == su0) {                         // diagonal block for big q-tile
#pragma unroll
        for (int g = 0; g < 4; ++g)
#pragma unroll
          for (int r = 0; r < 4; ++r) {
            int kcol = k0 + g * 16 + quad * 4 + r;
            if (kcol > qrow0) s0[g][r] = -__builtin_inff();
          }
      }

      // softmax big q-tile: p = exp2(s), pack -> Ps -> pf0
#pragma unroll
      for (int g = 0; g < 4; ++g) {
        bf16x4 pk = { (__bf16)EXP2(s0[g][0]), (__bf16)EXP2(s0[g][1]),
                      (__bf16)EXP2(s0[g][2]), (__bf16)EXP2(s0[g][3]) };
        *(bf16x4*)&Ps[wave][ln][g * 16 + quad * 4] = pk;
      }
      bf16x8 pf0[2], pf1[2];
#pragma unroll
      for (int ks = 0; ks < 2; ++ks)
        pf0[ks] = *(const bf16x8*)&Ps[wave][ln][ks * 32 + quad * 8];

      if (a1) {                                  // softmax small q-tile
        if (kb64 == su1) {
#pragma unroll
          for (int g = 0; g < 4; ++g)
#pragma unroll
            for (int r = 0; r < 4; ++r) {
              int kcol = k0 + g * 16 + quad * 4 + r;
              if (kcol > qrow1) s1[g][r] = -__builtin_inff();
            }
        }
#pragma unroll
        for (int g = 0; g < 4; ++g) {
          bf16x4 pk = { (__bf16)EXP2(s1[g][0]), (__bf16)EXP2(s1[g][1]),
                        (__bf16)EXP2(s1[g][2]), (__bf16)EXP2(s1[g][3]) };
          *(bf16x4*)&Ps[wave][ln][g * 16 + quad * 4] = pk;
        }
#pragma unroll
        for (int ks = 0; ks < 2; ++ks)
          pf1[ks] = *(const bf16x8*)&Ps[wave][ln][ks * 32 + quad * 8];
      } else {
        pf1[0] = bf16x8{};                       // exact zeros: o1/l1 += 0
        pf1[1] = bf16x8{};
      }

      // l += P @ ones (row sums land in O-row layout)
      l4[0] = __builtin_amdgcn_mfma_f32_16x16x32_bf16(pf0[0], onef, l4[0], 0, 0, 0);
      l4[0] = __builtin_amdgcn_mfma_f32_16x16x32_bf16(pf0[1], onef, l4[0], 0, 0, 0);
      l4[1] = __builtin_amdgcn_mfma_f32_16x16x32_bf16(pf1[0], onef, l4[1], 0, 0, 0);
      l4[1] = __builtin_amdgcn_mfma_f32_16x16x32_bf16(pf1[1], onef, l4[1], 0, 0, 0);

      // O += P V for BOTH q-tiles; each vf loaded once
#pragma unroll
      for (int g = 0; g < 4; ++g)
#pragma unroll
        for (int ks = 0; ks < 2; ++ks) {
          bf16x8 vf = *(const bf16x8*)&Vt[(g * 16 + ln) * 128 +
                                          (((h2 * 8 + ks * 4 + quad) ^ (ln & 7)) * 8)];
          o[0][g] = __builtin_amdgcn_mfma_f32_16x16x32_bf16(pf0[ks], vf, o[0][g], 0, 0, 0);
          o[1][g] = __builtin_amdgcn_mfma_f32_16x16x32_bf16(pf1[ks], vf, o[1][g], 0, 0, 0);
        }
    }
  }

  // epilogue: both q-tiles
#pragma unroll
  for (int qt = 0; qt < 2; ++qt) {
    float linv[4];
#pragma unroll
    for (int r = 0; r < 4; ++r) linv[r] = 1.0f / l4[qt][r];
#pragma unroll
    for (int g = 0; g < 4; ++g)
#pragma unroll
      for (int r = 0; r < 4; ++r) {
        int orow = qts[qt] * 128 + wave * 16 + quad * 4 + r;
        out[((size_t)b_ * Ss + orow) * Ee + h * HD + g * 16 + ln] = o[qt][g][r] * linv[r];
      }
  }
}

extern "C" void kernel_launch(void* const* d_in, const int* in_sizes, int n_in,
                              void* d_out, int out_size, void* d_ws, size_t ws_size,
                              hipStream_t stream) {
  const float* x  = (const float*)d_in[0];
  const float* Wq = (const float*)d_in[1];
  const float* bq = (const float*)d_in[2];
  const float* Wk = (const float*)d_in[3];
  const float* bk = (const float*)d_in[4];
  const float* Wv = (const float*)d_in[5];
  const float* bv = (const float*)d_in[6];
  float* out = (float*)d_out;

  unsigned short* ws  = (unsigned short*)d_ws;
  unsigned short* xb  = ws;                                   // 8388608
  unsigned short* wb  = ws + 8388608;                         // 3 * 1048576
  unsigned short* qkv = ws + 8388608 + 3 * 1048576;           // 3 * 8388608

  cvt_all<<<11264, 256, 0, stream>>>(x, Wq, Wk, Wv, xb, wb);
  qkv_gemm<<<dim3(64, 8, 3), 256, 0, stream>>>(xb, wb, bq, bk, bv, qkv);
  flash_attn<<<512, 512, 0, stream>>>(qkv, out);
}

// Round 9
// 199.869 us; speedup vs baseline: 1.0098x; 1.0098x over previous
//
#include <hip/hip_runtime.h>

// MaskedAttentionLayer B=4,S=2048,E=1024,H=16,HD=64; fp32 io, bf16 MFMA.
// R15: flash_attn gets the qkv-proven two-barrier counted-vmcnt pipeline:
// KVBLK=64, double-buffered K/V (LDS 50.4KB -> still 2 blocks/CU). Per tile:
// stage(kt+1); vmcnt(2); bar; all-asm LDS compute (DSR/DSW + lgkmcnt +
// sched_barrier, rule 18); bar. Loads for the next tile stay in flight under
// the full compute; only the peeled last tile drains vmcnt to 0. Unlike the
// NaN'd R9: TWO barriers/tile (stage-writes and compute-reads of any buffer
// always barrier-separated), no barriers inside guards, uniform loop bound.
// Zero-add MFMAs for the inactive small q-tile are guarded out (bit-identical:
// they added exact zeros). kf/vf loaded in halves to keep VGPR <= 128.
// qkv_gemm (R12 128^2, verified) + cvt_all unchanged.

typedef __bf16 bf16x8 __attribute__((ext_vector_type(8)));
typedef __bf16 bf16x4 __attribute__((ext_vector_type(4)));
typedef float f32x4 __attribute__((ext_vector_type(4)));
typedef unsigned short us8 __attribute__((ext_vector_type(8)));
typedef unsigned short us4 __attribute__((ext_vector_type(4)));

#define Bb 4
#define Ss 2048
#define Ee 1024
#define Hh 16
#define HD 64

#if __has_builtin(__builtin_amdgcn_exp2f)
#define EXP2(x) __builtin_amdgcn_exp2f(x)
#else
#define EXP2(x) exp2f(x)
#endif

__device__ __forceinline__ unsigned short f2bf(float f) {
  union { float f; unsigned u; } v; v.f = f;
  unsigned u = v.u;
  u += 0x7fffu + ((u >> 16) & 1u);   // RNE
  return (unsigned short)(u >> 16);
}

__device__ __forceinline__ void gl_lds16(const void* g, void* l) {
  __builtin_amdgcn_global_load_lds((const __attribute__((address_space(1))) void*)g,
                                   (__attribute__((address_space(3))) void*)l, 16, 0, 0);
}

// asm LDS ops with compile-time byte offsets; opaque to compiler waitcnt logic.
#define DSR(d, a, o) asm volatile("ds_read_b128 %0, %1 offset:" #o : "=v"(d) : "v"(a))
#define DSW(a, d, o) asm volatile("ds_write_b64 %0, %1 offset:" #o :: "v"(a), "v"(d) : "memory")
#define LGKM0 asm volatile("s_waitcnt lgkmcnt(0)" ::: "memory"); __builtin_amdgcn_sched_barrier(0)

// one kernel for all fp32->bf16 converts (x, Wq, Wk, Wv)
__global__ __launch_bounds__(256) void cvt_all(const float* __restrict__ x,
                                               const float* __restrict__ wq,
                                               const float* __restrict__ wk,
                                               const float* __restrict__ wv,
                                               unsigned short* __restrict__ xb,
                                               unsigned short* __restrict__ wb) {
  int i = blockIdx.x * 256 + threadIdx.x;   // float4 index, total 2883584
  const float* src; unsigned short* dst; int idx;
  if (i < 2097152)      { src = x;  dst = xb;                idx = i; }
  else if (i < 2359296) { src = wq; dst = wb;                idx = i - 2097152; }
  else if (i < 2621440) { src = wk; dst = wb + 1048576;      idx = i - 2359296; }
  else                  { src = wv; dst = wb + 2 * 1048576;  idx = i - 2621440; }
  float4 f = ((const float4*)src)[idx];
  us4 o = { f2bf(f.x), f2bf(f.y), f2bf(f.z), f2bf(f.w) };
  ((us4*)dst)[idx] = o;
}

// C[m,n] = sum_e X[m,e] W[n,e] + bias[n].  (R12 structure, verified)
// 128x128 tile, BK=64, 256 threads = 4 waves, dispersed-quadrant map.
// Grid (64,8,3) = 1536 blocks, 2 blocks/CU, 3 exact rounds.
// z=0 (Q): [b,h,s,d] scaled by 0.125*log2e.  z=1 (K): [b,h,s,d].  z=2 (V): [b,h,d,s].
__global__ __launch_bounds__(256, 2) void qkv_gemm(const unsigned short* __restrict__ xb,
                                                   const unsigned short* __restrict__ wb_all,
                                                   const float* __restrict__ bq,
                                                   const float* __restrict__ bk,
                                                   const float* __restrict__ bv,
                                                   unsigned short* __restrict__ qkv) {
  const int z = blockIdx.z;
  const unsigned short* wb = wb_all + (size_t)z * (Ee * Ee);
  const float* bias = (z == 0) ? bq : (z == 1) ? bk : bv;
  unsigned short* outb = qkv + (size_t)z * (Bb * Ss * Ee);
  const float osc = (z == 0) ? 0.180336880f : 1.0f;   // 0.125 * log2(e)

  __shared__ unsigned short SMEM[32768];   // 64 KiB: 2 x (A 8192 + B 8192 elems)

  const int t = threadIdx.x;
  const int wave = t >> 6, lane = t & 63, quad = lane >> 4, ln = lane & 15;
  const int wr = wave >> 1, wc = wave & 1;
  const int m0 = blockIdx.x * 128, n0 = blockIdx.y * 128;

  const int r32 = t >> 3;
  const int cs = ((t & 7) ^ (r32 & 7)) * 8;
  const int t8 = t * 8;
  const unsigned short* gA0 = xb + (size_t)(m0 + r32) * Ee + cs;       // A rows 0..63
  const unsigned short* gA1 = gA0 + 64 * Ee;                           // A rows 64..127
  const unsigned short* gB0 = wb + (size_t)(n0 + r32) * Ee + cs;       // B rows 0..63
  const unsigned short* gB1 = gB0 + 64 * Ee;                           // B rows 64..127

  const int swz0 = ((0 * 4 + quad) ^ (ln & 7)) * 16;
  const int swz1 = ((1 * 4 + quad) ^ (ln & 7)) * 16;
  int aA0 = (wr * 32 + ln) * 128 + swz0;
  int aA1 = (wr * 32 + ln) * 128 + swz1;
  int bA0 = 16384 + (wc * 32 + ln) * 128 + swz0;
  int bA1 = 16384 + (wc * 32 + ln) * 128 + swz1;

  f32x4 acc[2][2][2][2] = {};
  bf16x8 af[2][2], bf0[2][2], bf1[2][2];

  // ---- prologue: stage tile 0 into buf0, half order A0,B0,B1,A1 (vmcnt order!)
  gl_lds16(gA0,           &SMEM[t8]);
  gl_lds16(gA0 + 32 * Ee, &SMEM[t8 + 2048]);
  gl_lds16(gB0,           &SMEM[8192 + t8]);
  gl_lds16(gB0 + 32 * Ee, &SMEM[8192 + t8 + 2048]);
  gl_lds16(gB1,           &SMEM[12288 + t8]);
  gl_lds16(gB1 + 32 * Ee, &SMEM[12288 + t8 + 2048]);
  gl_lds16(gA1,           &SMEM[4096 + t8]);
  gl_lds16(gA1 + 32 * Ee, &SMEM[4096 + t8 + 2048]);

#pragma unroll 1
  for (int kt = 0; kt < 15; ++kt) {
    const int sbuf = ((kt & 1) << 14) ^ 16384;   // stage buffer (elems) for tile kt+1
    const int co = (kt + 1) * 64;                // next tile's K-column offset

    // ================ phase 0: C(qa0,qb0); reads A-lo + B-lo; stages A0(kt+1)
    asm volatile("s_waitcnt vmcnt(4)" ::: "memory");
    asm volatile("s_barrier" ::: "memory");
    DSR(af[0][0], aA0, 0);    DSR(af[1][0], aA0, 2048);
    DSR(af[0][1], aA1, 0);    DSR(af[1][1], aA1, 2048);
    DSR(bf0[0][0], bA0, 0);   DSR(bf0[1][0], bA0, 2048);
    DSR(bf0[0][1], bA1, 0);   DSR(bf0[1][1], bA1, 2048);
    gl_lds16(gA0 + co,           &SMEM[sbuf + t8]);
    gl_lds16(gA0 + co + 32 * Ee, &SMEM[sbuf + t8 + 2048]);
    asm volatile("s_barrier" ::: "memory");
    asm volatile("s_waitcnt lgkmcnt(0)" ::: "memory");
    __builtin_amdgcn_sched_barrier(0);
    __builtin_amdgcn_s_setprio(1);
#pragma unroll
    for (int kk = 0; kk < 2; ++kk)
#pragma unroll
      for (int i = 0; i < 2; ++i)
#pragma unroll
        for (int j = 0; j < 2; ++j)
          acc[0][0][i][j] = __builtin_amdgcn_mfma_f32_16x16x32_bf16(af[i][kk], bf0[j][kk], acc[0][0][i][j], 0, 0, 0);
    __builtin_amdgcn_s_setprio(0);
    __builtin_amdgcn_sched_barrier(0);

    // ================ phase 1: C(qa0,qb1); reads B-hi; stages B0(kt+1)
    asm volatile("s_waitcnt vmcnt(4)" ::: "memory");
    asm volatile("s_barrier" ::: "memory");
    DSR(bf1[0][0], bA0, 8192); DSR(bf1[1][0], bA0, 10240);
    DSR(bf1[0][1], bA1, 8192); DSR(bf1[1][1], bA1, 10240);
    gl_lds16(gB0 + co,           &SMEM[sbuf + 8192 + t8]);
    gl_lds16(gB0 + co + 32 * Ee, &SMEM[sbuf + 8192 + t8 + 2048]);
    asm volatile("s_barrier" ::: "memory");
    asm volatile("s_waitcnt lgkmcnt(0)" ::: "memory");
    __builtin_amdgcn_sched_barrier(0);
    __builtin_amdgcn_s_setprio(1);
#pragma unroll
    for (int kk = 0; kk < 2; ++kk)
#pragma unroll
      for (int i = 0; i < 2; ++i)
#pragma unroll
        for (int j = 0; j < 2; ++j)
          acc[0][1][i][j] = __builtin_amdgcn_mfma_f32_16x16x32_bf16(af[i][kk], bf1[j][kk], acc[0][1][i][j], 0, 0, 0);
    __builtin_amdgcn_s_setprio(0);
    __builtin_amdgcn_sched_barrier(0);

    // ================ phase 2: C(qa1,qb0); reads A-hi; stages B1(kt+1)
    asm volatile("s_waitcnt vmcnt(4)" ::: "memory");
    asm volatile("s_barrier" ::: "memory");
    DSR(af[0][0], aA0, 8192); DSR(af[1][0], aA0, 10240);
    DSR(af[0][1], aA1, 8192); DSR(af[1][1], aA1, 10240);
    gl_lds16(gB1 + co,           &SMEM[sbuf + 12288 + t8]);
    gl_lds16(gB1 + co + 32 * Ee, &SMEM[sbuf + 12288 + t8 + 2048]);
    asm volatile("s_barrier" ::: "memory");
    asm volatile("s_waitcnt lgkmcnt(0)" ::: "memory");
    __builtin_amdgcn_sched_barrier(0);
    __builtin_amdgcn_s_setprio(1);
#pragma unroll
    for (int kk = 0; kk < 2; ++kk)
#pragma unroll
      for (int i = 0; i < 2; ++i)
#pragma unroll
        for (int j = 0; j < 2; ++j)
          acc[1][0][i][j] = __builtin_amdgcn_mfma_f32_16x16x32_bf16(af[i][kk], bf0[j][kk], acc[1][0][i][j], 0, 0, 0);
    __builtin_amdgcn_s_setprio(0);
    __builtin_amdgcn_sched_barrier(0);

    // ================ phase 3: C(qa1,qb1); no reads; stages A1(kt+1)
    asm volatile("s_barrier" ::: "memory");
    gl_lds16(gA1 + co,           &SMEM[sbuf + 4096 + t8]);
    gl_lds16(gA1 + co + 32 * Ee, &SMEM[sbuf + 4096 + t8 + 2048]);
    asm volatile("s_barrier" ::: "memory");
    __builtin_amdgcn_sched_barrier(0);
    __builtin_amdgcn_s_setprio(1);
#pragma unroll
    for (int kk = 0; kk < 2; ++kk)
#pragma unroll
      for (int i = 0; i < 2; ++i)
#pragma unroll
        for (int j = 0; j < 2; ++j)
          acc[1][1][i][j] = __builtin_amdgcn_mfma_f32_16x16x32_bf16(af[i][kk], bf1[j][kk], acc[1][1][i][j], 0, 0, 0);
    __builtin_amdgcn_s_setprio(0);
    __builtin_amdgcn_sched_barrier(0);

    aA0 ^= 32768; aA1 ^= 32768; bA0 ^= 32768; bA1 ^= 32768;
  }

  // ---- peeled tile 15: only place vmcnt drains to 0 (bases now at buf1)
  {
    asm volatile("s_waitcnt vmcnt(0)" ::: "memory");
    asm volatile("s_barrier" ::: "memory");
    DSR(af[0][0], aA0, 0);    DSR(af[1][0], aA0, 2048);
    DSR(af[0][1], aA1, 0);    DSR(af[1][1], aA1, 2048);
    DSR(bf0[0][0], bA0, 0);   DSR(bf0[1][0], bA0, 2048);
    DSR(bf0[0][1], bA1, 0);   DSR(bf0[1][1], bA1, 2048);
    DSR(bf1[0][0], bA0, 8192); DSR(bf1[1][0], bA0, 10240);
    DSR(bf1[0][1], bA1, 8192); DSR(bf1[1][1], bA1, 10240);
    asm volatile("s_waitcnt lgkmcnt(0)" ::: "memory");
    __builtin_amdgcn_sched_barrier(0);
#pragma unroll
    for (int kk = 0; kk < 2; ++kk)
#pragma unroll
      for (int i = 0; i < 2; ++i)
#pragma unroll
        for (int j = 0; j < 2; ++j) {
          acc[0][0][i][j] = __builtin_amdgcn_mfma_f32_16x16x32_bf16(af[i][kk], bf0[j][kk], acc[0][0][i][j], 0, 0, 0);
          acc[0][1][i][j] = __builtin_amdgcn_mfma_f32_16x16x32_bf16(af[i][kk], bf1[j][kk], acc[0][1][i][j], 0, 0, 0);
        }
    __builtin_amdgcn_sched_barrier(0);
    DSR(af[0][0], aA0, 8192); DSR(af[1][0], aA0, 10240);
    DSR(af[0][1], aA1, 8192); DSR(af[1][1], aA1, 10240);
    asm volatile("s_waitcnt lgkmcnt(0)" ::: "memory");
    __builtin_amdgcn_sched_barrier(0);
#pragma unroll
    for (int kk = 0; kk < 2; ++kk)
#pragma unroll
      for (int i = 0; i < 2; ++i)
#pragma unroll
        for (int j = 0; j < 2; ++j) {
          acc[1][0][i][j] = __builtin_amdgcn_mfma_f32_16x16x32_bf16(af[i][kk], bf0[j][kk], acc[1][0][i][j], 0, 0, 0);
          acc[1][1][i][j] = __builtin_amdgcn_mfma_f32_16x16x32_bf16(af[i][kk], bf1[j][kk], acc[1][1][i][j], 0, 0, 0);
        }
    __builtin_amdgcn_sched_barrier(0);
  }

  // ---- epilogue
  float biasj[2][2];
#pragma unroll
  for (int qb = 0; qb < 2; ++qb)
#pragma unroll
    for (int j = 0; j < 2; ++j)
      biasj[qb][j] = bias[n0 + qb * 64 + wc * 32 + j * 16 + ln];

  if (z != 2) {
#pragma unroll
    for (int qa = 0; qa < 2; ++qa)
#pragma unroll
      for (int qb = 0; qb < 2; ++qb)
#pragma unroll
        for (int i = 0; i < 2; ++i)
#pragma unroll
          for (int j = 0; j < 2; ++j)
#pragma unroll
            for (int r = 0; r < 4; ++r) {
              int m = m0 + qa * 64 + wr * 32 + i * 16 + quad * 4 + r;
              int n = n0 + qb * 64 + wc * 32 + j * 16 + ln;
              int b_ = m >> 11, s = m & 2047;
              int h = n >> 6, d = n & 63;
              outb[(((size_t)b_ * Hh + h) * Ss + s) * HD + d] =
                  f2bf((acc[qa][qb][i][j][r] + biasj[qb][j]) * osc);
            }
  } else {
    // V: transpose to [b,h,d,s] through LDS (128x128 fits in one pass)
    __syncthreads();
#pragma unroll
    for (int qa = 0; qa < 2; ++qa)
#pragma unroll
      for (int qb = 0; qb < 2; ++qb)
#pragma unroll
        for (int i = 0; i < 2; ++i)
#pragma unroll
          for (int j = 0; j < 2; ++j)
#pragma unroll
            for (int r = 0; r < 4; ++r) {
              int nc = qb * 64 + wc * 32 + j * 16 + ln;
              int mr = qa * 64 + wr * 32 + i * 16 + quad * 4 + r;
              SMEM[nc * 136 + mr] = f2bf(acc[qa][qb][i][j][r] + biasj[qb][j]);
            }
    __syncthreads();
    int nr = t >> 1, mh = t & 1;
    int n = n0 + nr, h = n >> 6, d = n & 63;
    int b_ = m0 >> 11;
    int s0 = (m0 & 2047) + mh * 64;
#pragma unroll
    for (int q = 0; q < 8; ++q) {
      us8 vdat = *(const us8*)&SMEM[nr * 136 + mh * 64 + q * 8];
      *(us8*)&outb[(((size_t)b_ * Hh + h) * HD + d) * Ss + s0 + q * 8] = vdat;
    }
  }
}

// Flash attention, causal, S^T = K Q^T, max-free exp2 softmax.
// R15: grid 512 (64 bh x 8 p), 512 thr / 8 waves, 2 blocks/CU. Block p owns
// q-tiles {15-p, p}; wave w owns 16-row strip w*16 of each. KVBLK=64,
// double-buffered K/V, two-barrier counted-vmcnt pipeline (qkv-proven):
// per tile {stage(kt+1); vmcnt(2); bar; asm-LDS compute; bar}. K/V fragments
// shared by both q-tiles; inactive small tile fully guarded (wave-uniform,
// no barriers inside; removing exact-zero adds is bit-identical).
// LDS elems: Ks b0 [0,4096) b1 [4096,8192); Vt b0 [8192,12288) b1 [12288,16384);
// Ps [16384,25600). 51200 B total.
__global__ __launch_bounds__(512, 2) void flash_attn(const unsigned short* __restrict__ qkv,
                                                     float* __restrict__ out) {
  const int id = blockIdx.x;
  const int bh = id & 63;
  const int p = id >> 6;            // 0..7
  const int b_ = bh >> 4, h = bh & 15;

  const unsigned short* qb  = qkv + (size_t)bh * (Ss * HD);
  const unsigned short* kb  = qkv + (size_t)(64 + bh) * (Ss * HD);
  const unsigned short* vtb = qkv + (size_t)(128 + bh) * (Ss * HD);  // [d][s]

  __shared__ __bf16 LDS[25600];        // 51200 B (see header comment)

  const int t = threadIdx.x;
  const int wave = t >> 6, lane = t & 63, quad = lane >> 4, ln = lane & 15;
  const int uw = wave >> 2;            // 64-row subtile half within each q-tile

  // staging: thread t -> row r6 = t>>3 (0..63), global chunk (t&7)^(r6&7),
  // LDS linear dest t*8 elems (both-sides swizzle).
  const int r6 = t >> 3;
  const int cstage = ((t & 7) ^ (r6 & 7)) * 8;
  const int t8 = t * 8;

  const int qts[2] = { 15 - p, p };    // big q-tile first; small reuses staging
  const int KTB = 2 * qts[0] + 2;      // 64-col K/V tiles (block-uniform)
  const int su0 = 2 * qts[0] + uw;     // this wave's subtile index, big q-tile
  const int su1 = 2 * qts[1] + uw;     // ... small q-tile
  const int qrow0 = qts[0] * 128 + wave * 16 + ln;
  const int qrow1 = qts[1] * 128 + wave * 16 + ln;

  // asm LDS byte bases. kf/vf row = g*16+ln, chunk slot = (ks*4+quad)^(ln&7);
  // row stride 128 B, g step 2048 B. Vt base = ka + 16384 B. Buffer toggle ^8192.
  int ka0 = ln * 128 + ((quad ^ (ln & 7)) * 16);
  int ka1 = ln * 128 + (((4 + quad) ^ (ln & 7)) * 16);
  // Ps (per-wave private rows): write cols g*16+quad*4 (b64), read cols ks*32+quad*8 (b128)
  const int pw = (16384 + (wave * 16 + ln) * 72 + quad * 4) * 2;
  const int pr = (16384 + (wave * 16 + ln) * 72 + quad * 8) * 2;

  bf16x8 qf[2][2];                     // [qt][ks] — loaded BEFORE any gl_lds16
#pragma unroll
  for (int qt = 0; qt < 2; ++qt)
#pragma unroll
    for (int ks = 0; ks < 2; ++ks)
      qf[qt][ks] = *(const bf16x8*)(qb + (size_t)(qts[qt] * 128 + wave * 16 + ln) * HD +
                                    ks * 32 + quad * 8);

  bf16x8 onef;
#pragma unroll
  for (int j = 0; j < 8; ++j) onef[j] = (__bf16)1.0f;

  f32x4 o[2][4] = {};                  // [qt][g]
  f32x4 l4[2] = {};                    // [qt]

  // compute body for one 64-col K/V tile (NO barriers inside; wave-uniform guards)
  auto body = [&](int kt) {
    if (kt > su0) return;              // fully masked for this wave
    const bool a1 = (kt <= su1);
    const int k0 = kt * 64;
    f32x4 s0[4] = {}, s1[4] = {};
    bf16x8 kf[2][2];

    // ---- S^T = K Q^T, g-half 0 (g=0,1)
    DSR(kf[0][0], ka0, 0);    DSR(kf[1][0], ka0, 2048);
    DSR(kf[0][1], ka1, 0);    DSR(kf[1][1], ka1, 2048);
    LGKM0;
#pragma unroll
    for (int ks = 0; ks < 2; ++ks) {
      s0[0] = __builtin_amdgcn_mfma_f32_16x16x32_bf16(kf[0][ks], qf[0][ks], s0[0], 0, 0, 0);
      s0[1] = __builtin_amdgcn_mfma_f32_16x16x32_bf16(kf[1][ks], qf[0][ks], s0[1], 0, 0, 0);
    }
    if (a1)
#pragma unroll
      for (int ks = 0; ks < 2; ++ks) {
        s1[0] = __builtin_amdgcn_mfma_f32_16x16x32_bf16(kf[0][ks], qf[1][ks], s1[0], 0, 0, 0);
        s1[1] = __builtin_amdgcn_mfma_f32_16x16x32_bf16(kf[1][ks], qf[1][ks], s1[1], 0, 0, 0);
      }
    // ---- g-half 1 (g=2,3)
    DSR(kf[0][0], ka0, 4096); DSR(kf[1][0], ka0, 6144);
    DSR(kf[0][1], ka1, 4096); DSR(kf[1][1], ka1, 6144);
    LGKM0;
#pragma unroll
    for (int ks = 0; ks < 2; ++ks) {
      s0[2] = __builtin_amdgcn_mfma_f32_16x16x32_bf16(kf[0][ks], qf[0][ks], s0[2], 0, 0, 0);
      s0[3] = __builtin_amdgcn_mfma_f32_16x16x32_bf16(kf[1][ks], qf[0][ks], s0[3], 0, 0, 0);
    }
    if (a1)
#pragma unroll
      for (int ks = 0; ks < 2; ++ks) {
        s1[2] = __builtin_amdgcn_mfma_f32_16x16x32_bf16(kf[0][ks], qf[1][ks], s1[2], 0, 0, 0);
        s1[3] = __builtin_amdgcn_mfma_f32_16x16x32_bf16(kf[1][ks], qf[1][ks], s1[3], 0, 0, 0);
      }

    // ---- softmax big q-tile: mask diagonal, exp2, pack -> Ps -> pf0
    if (kt == su0) {
#pragma unroll
      for (int g = 0; g < 4; ++g)
#pragma unroll
        for (int r = 0; r < 4; ++r) {
          int kcol = k0 + g * 16 + quad * 4 + r;
          if (kcol > qrow0) s0[g][r] = -__builtin_inff();
        }
    }
    {
      bf16x4 pk;
      pk = bf16x4{ (__bf16)EXP2(s0[0][0]), (__bf16)EXP2(s0[0][1]), (__bf16)EXP2(s0[0][2]), (__bf16)EXP2(s0[0][3]) };
      DSW(pw, pk, 0);
      pk = bf16x4{ (__bf16)EXP2(s0[1][0]), (__bf16)EXP2(s0[1][1]), (__bf16)EXP2(s0[1][2]), (__bf16)EXP2(s0[1][3]) };
      DSW(pw, pk, 32);
      pk = bf16x4{ (__bf16)EXP2(s0[2][0]), (__bf16)EXP2(s0[2][1]), (__bf16)EXP2(s0[2][2]), (__bf16)EXP2(s0[2][3]) };
      DSW(pw, pk, 64);
      pk = bf16x4{ (__bf16)EXP2(s0[3][0]), (__bf16)EXP2(s0[3][1]), (__bf16)EXP2(s0[3][2]), (__bf16)EXP2(s0[3][3]) };
      DSW(pw, pk, 96);
    }
    bf16x8 pf0[2], pf1[2];
    DSR(pf0[0], pr, 0); DSR(pf0[1], pr, 64);
    LGKM0;                              // pf0 in regs; Ps now free for reuse

    if (a1) {                           // softmax small q-tile (overwrites Ps)
      if (kt == su1) {
#pragma unroll
        for (int g = 0; g < 4; ++g)
#pragma unroll
          for (int r = 0; r < 4; ++r) {
            int kcol = k0 + g * 16 + quad * 4 + r;
            if (kcol > qrow1) s1[g][r] = -__builtin_inff();
          }
      }
      bf16x4 pk;
      pk = bf16x4{ (__bf16)EXP2(s1[0][0]), (__bf16)EXP2(s1[0][1]), (__bf16)EXP2(s1[0][2]), (__bf16)EXP2(s1[0][3]) };
      DSW(pw, pk, 0);
      pk = bf16x4{ (__bf16)EXP2(s1[1][0]), (__bf16)EXP2(s1[1][1]), (__bf16)EXP2(s1[1][2]), (__bf16)EXP2(s1[1][3]) };
      DSW(pw, pk, 32);
      pk = bf16x4{ (__bf16)EXP2(s1[2][0]), (__bf16)EXP2(s1[2][1]), (__bf16)EXP2(s1[2][2]), (__bf16)EXP2(s1[2][3]) };
      DSW(pw, pk, 64);
      pk = bf16x4{ (__bf16)EXP2(s1[3][0]), (__bf16)EXP2(s1[3][1]), (__bf16)EXP2(s1[3][2]), (__bf16)EXP2(s1[3][3]) };
      DSW(pw, pk, 96);
      DSR(pf1[0], pr, 0); DSR(pf1[1], pr, 64);
      LGKM0;
    }

    // ---- l += P @ ones
    l4[0] = __builtin_amdgcn_mfma_f32_16x16x32_bf16(pf0[0], onef, l4[0], 0, 0, 0);
    l4[0] = __builtin_amdgcn_mfma_f32_16x16x32_bf16(pf0[1], onef, l4[0], 0, 0, 0);
    if (a1) {
      l4[1] = __builtin_amdgcn_mfma_f32_16x16x32_bf16(pf1[0], onef, l4[1], 0, 0, 0);
      l4[1] = __builtin_amdgcn_mfma_f32_16x16x32_bf16(pf1[1], onef, l4[1], 0, 0, 0);
    }

    // ---- O += P V, vf g-half 0 then 1 (vf shared by both q-tiles)
    DSR(kf[0][0], ka0, 16384); DSR(kf[1][0], ka0, 18432);
    DSR(kf[0][1], ka1, 16384); DSR(kf[1][1], ka1, 18432);
    LGKM0;
#pragma unroll
    for (int ks = 0; ks < 2; ++ks) {
      o[0][0] = __builtin_amdgcn_mfma_f32_16x16x32_bf16(pf0[ks], kf[0][ks], o[0][0], 0, 0, 0);
      o[0][1] = __builtin_amdgcn_mfma_f32_16x16x32_bf16(pf0[ks], kf[1][ks], o[0][1], 0, 0, 0);
    }
    if (a1)
#pragma unroll
      for (int ks = 0; ks < 2; ++ks) {
        o[1][0] = __builtin_amdgcn_mfma_f32_16x16x32_bf16(pf1[ks], kf[0][ks], o[1][0], 0, 0, 0);
        o[1][1] = __builtin_amdgcn_mfma_f32_16x16x32_bf16(pf1[ks], kf[1][ks], o[1][1], 0, 0, 0);
      }
    DSR(kf[0][0], ka0, 20480); DSR(kf[1][0], ka0, 22528);
    DSR(kf[0][1], ka1, 20480); DSR(kf[1][1], ka1, 22528);
    LGKM0;
#pragma unroll
    for (int ks = 0; ks < 2; ++ks) {
      o[0][2] = __builtin_amdgcn_mfma_f32_16x16x32_bf16(pf0[ks], kf[0][ks], o[0][2], 0, 0, 0);
      o[0][3] = __builtin_amdgcn_mfma_f32_16x16x32_bf16(pf0[ks], kf[1][ks], o[0][3], 0, 0, 0);
    }
    if (a1)
#pragma unroll
      for (int ks = 0; ks < 2; ++ks) {
        o[1][2] = __builtin_amdgcn_mfma_f32_16x16x32_bf16(pf1[ks], kf[0][ks], o[1][2], 0, 0, 0);
        o[1][3] = __builtin_amdgcn_mfma_f32_16x16x32_bf16(pf1[ks], kf[1][ks], o[1][3], 0, 0, 0);
      }
  };

  // ---- prologue: stage tile 0 -> buf0 (after qf loads: oldest vmcnt entries are qf)
  gl_lds16(kb + r6 * HD + cstage,  &LDS[t8]);
  gl_lds16(vtb + r6 * Ss + cstage, &LDS[8192 + t8]);

#pragma unroll 1
  for (int kt = 0; kt < KTB - 1; ++kt) {
    const int sb = (kt & 1) ^ 1;       // stage buffer for tile kt+1
    gl_lds16(kb + (size_t)(kt + 1) * (64 * HD) + r6 * HD + cstage, &LDS[sb * 4096 + t8]);
    gl_lds16(vtb + (kt + 1) * 64 + r6 * Ss + cstage,               &LDS[8192 + sb * 4096 + t8]);
    asm volatile("s_waitcnt vmcnt(2)" ::: "memory");   // tile kt's K,V arrived
    asm volatile("s_barrier" ::: "memory");
    body(kt);
    asm volatile("s_barrier" ::: "memory");            // all reads done before next stage
    ka0 ^= 8192; ka1 ^= 8192;
  }
  // peeled last tile: only vmcnt(0) drain
  asm volatile("s_waitcnt vmcnt(0)" ::: "memory");
  asm volatile("s_barrier" ::: "memory");
  body(KTB - 1);

  // epilogue: both q-tiles
#pragma unroll
  for (int qt = 0; qt < 2; ++qt) {
    float linv[4];
#pragma unroll
    for (int r = 0; r < 4; ++r) linv[r] = 1.0f / l4[qt][r];
#pragma unroll
    for (int g = 0; g < 4; ++g)
#pragma unroll
      for (int r = 0; r < 4; ++r) {
        int orow = qts[qt] * 128 + wave * 16 + quad * 4 + r;
        out[((size_t)b_ * Ss + orow) * Ee + h * HD + g * 16 + ln] = o[qt][g][r] * linv[r];
      }
  }
}

extern "C" void kernel_launch(void* const* d_in, const int* in_sizes, int n_in,
                              void* d_out, int out_size, void* d_ws, size_t ws_size,
                              hipStream_t stream) {
  const float* x  = (const float*)d_in[0];
  const float* Wq = (const float*)d_in[1];
  const float* bq = (const float*)d_in[2];
  const float* Wk = (const float*)d_in[3];
  const float* bk = (const float*)d_in[4];
  const float* Wv = (const float*)d_in[5];
  const float* bv = (const float*)d_in[6];
  float* out = (float*)d_out;

  unsigned short* ws  = (unsigned short*)d_ws;
  unsigned short* xb  = ws;                                   // 8388608
  unsigned short* wb  = ws + 8388608;                         // 3 * 1048576
  unsigned short* qkv = ws + 8388608 + 3 * 1048576;           // 3 * 8388608

  cvt_all<<<11264, 256, 0, stream>>>(x, Wq, Wk, Wv, xb, wb);
  qkv_gemm<<<dim3(64, 8, 3), 256, 0, stream>>>(xb, wb, bq, bk, bv, qkv);
  flash_attn<<<512, 512, 0, stream>>>(qkv, out);
}

// Round 10
// 194.864 us; speedup vs baseline: 1.0358x; 1.0257x over previous
//
#include <hip/hip_runtime.h>

// MaskedAttentionLayer B=4,S=2048,E=1024,H=16,HD=64; fp32 io, bf16 MFMA.
// R16: qkv_gemm main loop fused from 4 phases/K-tile to ONE body/K-tile
// (the R15-flash-proven shape): {stage kt+1 (8 gl_lds16); vmcnt(8); bar;
// 16 DSR; lgkm; setprio; 32 MFMA (quadrant order 00,01,10,11, kk/i/j
// nesting unchanged -> bit-identical chains); bar}. Barriers 128->32 per
// block, lgkm waits 4->1 per tile. Staging addrs, swizzle, epilogue, grid
// (64,8,3), LDS 64KB/2blocks-per-CU all unchanged from R12.
// flash_attn (R15 counted-vmcnt, verified) + cvt_all unchanged.

typedef __bf16 bf16x8 __attribute__((ext_vector_type(8)));
typedef __bf16 bf16x4 __attribute__((ext_vector_type(4)));
typedef float f32x4 __attribute__((ext_vector_type(4)));
typedef unsigned short us8 __attribute__((ext_vector_type(8)));
typedef unsigned short us4 __attribute__((ext_vector_type(4)));

#define Bb 4
#define Ss 2048
#define Ee 1024
#define Hh 16
#define HD 64

#if __has_builtin(__builtin_amdgcn_exp2f)
#define EXP2(x) __builtin_amdgcn_exp2f(x)
#else
#define EXP2(x) exp2f(x)
#endif

__device__ __forceinline__ unsigned short f2bf(float f) {
  union { float f; unsigned u; } v; v.f = f;
  unsigned u = v.u;
  u += 0x7fffu + ((u >> 16) & 1u);   // RNE
  return (unsigned short)(u >> 16);
}

__device__ __forceinline__ void gl_lds16(const void* g, void* l) {
  __builtin_amdgcn_global_load_lds((const __attribute__((address_space(1))) void*)g,
                                   (__attribute__((address_space(3))) void*)l, 16, 0, 0);
}

// asm LDS ops with compile-time byte offsets; opaque to compiler waitcnt logic.
#define DSR(d, a, o) asm volatile("ds_read_b128 %0, %1 offset:" #o : "=v"(d) : "v"(a))
#define DSW(a, d, o) asm volatile("ds_write_b64 %0, %1 offset:" #o :: "v"(a), "v"(d) : "memory")
#define LGKM0 asm volatile("s_waitcnt lgkmcnt(0)" ::: "memory"); __builtin_amdgcn_sched_barrier(0)

// one kernel for all fp32->bf16 converts (x, Wq, Wk, Wv)
__global__ __launch_bounds__(256) void cvt_all(const float* __restrict__ x,
                                               const float* __restrict__ wq,
                                               const float* __restrict__ wk,
                                               const float* __restrict__ wv,
                                               unsigned short* __restrict__ xb,
                                               unsigned short* __restrict__ wb) {
  int i = blockIdx.x * 256 + threadIdx.x;   // float4 index, total 2883584
  const float* src; unsigned short* dst; int idx;
  if (i < 2097152)      { src = x;  dst = xb;                idx = i; }
  else if (i < 2359296) { src = wq; dst = wb;                idx = i - 2097152; }
  else if (i < 2621440) { src = wk; dst = wb + 1048576;      idx = i - 2359296; }
  else                  { src = wv; dst = wb + 2 * 1048576;  idx = i - 2621440; }
  float4 f = ((const float4*)src)[idx];
  us4 o = { f2bf(f.x), f2bf(f.y), f2bf(f.z), f2bf(f.w) };
  ((us4*)dst)[idx] = o;
}

// C[m,n] = sum_e X[m,e] W[n,e] + bias[n].
// 128x128 tile, BK=64, 256 threads = 4 waves, dispersed-quadrant map
// (wave (wr,wc) owns 32x32 of each 64x64 C-quadrant). LDS 64 KiB:
// 2 x (A[128][64] + B[128][64]) bf16, XOR chunk swizzle.
// R16: ONE fused body per K-tile (see header). Grid (64,8,3) = 1536 blocks,
// 2 blocks/CU, 3 exact rounds.
// z=0 (Q): [b,h,s,d] scaled by 0.125*log2e.  z=1 (K): [b,h,s,d].  z=2 (V): [b,h,d,s].
__global__ __launch_bounds__(256, 2) void qkv_gemm(const unsigned short* __restrict__ xb,
                                                   const unsigned short* __restrict__ wb_all,
                                                   const float* __restrict__ bq,
                                                   const float* __restrict__ bk,
                                                   const float* __restrict__ bv,
                                                   unsigned short* __restrict__ qkv) {
  const int z = blockIdx.z;
  const unsigned short* wb = wb_all + (size_t)z * (Ee * Ee);
  const float* bias = (z == 0) ? bq : (z == 1) ? bk : bv;
  unsigned short* outb = qkv + (size_t)z * (Bb * Ss * Ee);
  const float osc = (z == 0) ? 0.180336880f : 1.0f;   // 0.125 * log2(e)

  __shared__ unsigned short SMEM[32768];   // 64 KiB: 2 x (A 8192 + B 8192 elems)

  const int t = threadIdx.x;
  const int wave = t >> 6, lane = t & 63, quad = lane >> 4, ln = lane & 15;
  const int wr = wave >> 1, wc = wave & 1;
  const int m0 = blockIdx.x * 128, n0 = blockIdx.y * 128;

  const int r32 = t >> 3;
  const int cs = ((t & 7) ^ (r32 & 7)) * 8;
  const int t8 = t * 8;
  const unsigned short* gA0 = xb + (size_t)(m0 + r32) * Ee + cs;       // A rows 0..63
  const unsigned short* gA1 = gA0 + 64 * Ee;                           // A rows 64..127
  const unsigned short* gB0 = wb + (size_t)(n0 + r32) * Ee + cs;       // B rows 0..63
  const unsigned short* gB1 = gB0 + 64 * Ee;                           // B rows 64..127

  const int swz0 = ((0 * 4 + quad) ^ (ln & 7)) * 16;
  const int swz1 = ((1 * 4 + quad) ^ (ln & 7)) * 16;
  int aA0 = (wr * 32 + ln) * 128 + swz0;
  int aA1 = (wr * 32 + ln) * 128 + swz1;
  int bA0 = 16384 + (wc * 32 + ln) * 128 + swz0;
  int bA1 = 16384 + (wc * 32 + ln) * 128 + swz1;

  f32x4 acc[2][2][2][2] = {};
  bf16x8 af0[2][2], af1[2][2], bf0[2][2], bf1[2][2];   // lo/hi A, lo/hi B

  // ---- prologue: stage tile 0 into buf0 (8 calls)
  gl_lds16(gA0,           &SMEM[t8]);
  gl_lds16(gA0 + 32 * Ee, &SMEM[t8 + 2048]);
  gl_lds16(gB0,           &SMEM[8192 + t8]);
  gl_lds16(gB0 + 32 * Ee, &SMEM[8192 + t8 + 2048]);
  gl_lds16(gB1,           &SMEM[12288 + t8]);
  gl_lds16(gB1 + 32 * Ee, &SMEM[12288 + t8 + 2048]);
  gl_lds16(gA1,           &SMEM[4096 + t8]);
  gl_lds16(gA1 + 32 * Ee, &SMEM[4096 + t8 + 2048]);

#pragma unroll 1
  for (int kt = 0; kt < 15; ++kt) {
    const int sbuf = ((kt & 1) << 14) ^ 16384;   // stage buffer (elems) for tile kt+1
    const int co = (kt + 1) * 64;                // next tile's K-column offset

    // ---- stage ALL of tile kt+1 (prev iteration's trailing barrier ensures
    // every wave finished reading this buffer)
    gl_lds16(gA0 + co,           &SMEM[sbuf + t8]);
    gl_lds16(gA0 + co + 32 * Ee, &SMEM[sbuf + t8 + 2048]);
    gl_lds16(gB0 + co,           &SMEM[sbuf + 8192 + t8]);
    gl_lds16(gB0 + co + 32 * Ee, &SMEM[sbuf + 8192 + t8 + 2048]);
    gl_lds16(gB1 + co,           &SMEM[sbuf + 12288 + t8]);
    gl_lds16(gB1 + co + 32 * Ee, &SMEM[sbuf + 12288 + t8 + 2048]);
    gl_lds16(gA1 + co,           &SMEM[sbuf + 4096 + t8]);
    gl_lds16(gA1 + co + 32 * Ee, &SMEM[sbuf + 4096 + t8 + 2048]);

    // tile kt's 8 loads arrived; kt+1's 8 stay in flight under the compute
    asm volatile("s_waitcnt vmcnt(8)" ::: "memory");
    asm volatile("s_barrier" ::: "memory");

    // ---- read ALL fragments of tile kt
    DSR(af0[0][0], aA0, 0);    DSR(af0[1][0], aA0, 2048);
    DSR(af0[0][1], aA1, 0);    DSR(af0[1][1], aA1, 2048);
    DSR(af1[0][0], aA0, 8192); DSR(af1[1][0], aA0, 10240);
    DSR(af1[0][1], aA1, 8192); DSR(af1[1][1], aA1, 10240);
    DSR(bf0[0][0], bA0, 0);    DSR(bf0[1][0], bA0, 2048);
    DSR(bf0[0][1], bA1, 0);    DSR(bf0[1][1], bA1, 2048);
    DSR(bf1[0][0], bA0, 8192); DSR(bf1[1][0], bA0, 10240);
    DSR(bf1[0][1], bA1, 8192); DSR(bf1[1][1], bA1, 10240);
    LGKM0;
    __builtin_amdgcn_s_setprio(1);
    // quadrant (0,0): af-lo x bf0   [same chain order as R12 phase 0]
#pragma unroll
    for (int kk = 0; kk < 2; ++kk)
#pragma unroll
      for (int i = 0; i < 2; ++i)
#pragma unroll
        for (int j = 0; j < 2; ++j)
          acc[0][0][i][j] = __builtin_amdgcn_mfma_f32_16x16x32_bf16(af0[i][kk], bf0[j][kk], acc[0][0][i][j], 0, 0, 0);
    // quadrant (0,1): af-lo x bf1   [phase 1]
#pragma unroll
    for (int kk = 0; kk < 2; ++kk)
#pragma unroll
      for (int i = 0; i < 2; ++i)
#pragma unroll
        for (int j = 0; j < 2; ++j)
          acc[0][1][i][j] = __builtin_amdgcn_mfma_f32_16x16x32_bf16(af0[i][kk], bf1[j][kk], acc[0][1][i][j], 0, 0, 0);
    // quadrant (1,0): af-hi x bf0   [phase 2]
#pragma unroll
    for (int kk = 0; kk < 2; ++kk)
#pragma unroll
      for (int i = 0; i < 2; ++i)
#pragma unroll
        for (int j = 0; j < 2; ++j)
          acc[1][0][i][j] = __builtin_amdgcn_mfma_f32_16x16x32_bf16(af1[i][kk], bf0[j][kk], acc[1][0][i][j], 0, 0, 0);
    // quadrant (1,1): af-hi x bf1   [phase 3]
#pragma unroll
    for (int kk = 0; kk < 2; ++kk)
#pragma unroll
      for (int i = 0; i < 2; ++i)
#pragma unroll
        for (int j = 0; j < 2; ++j)
          acc[1][1][i][j] = __builtin_amdgcn_mfma_f32_16x16x32_bf16(af1[i][kk], bf1[j][kk], acc[1][1][i][j], 0, 0, 0);
    __builtin_amdgcn_s_setprio(0);
    __builtin_amdgcn_sched_barrier(0);
    asm volatile("s_barrier" ::: "memory");      // reads done before next stage

    aA0 ^= 32768; aA1 ^= 32768; bA0 ^= 32768; bA1 ^= 32768;
  }

  // ---- peeled tile 15: only place vmcnt drains to 0 (bases now at buf1)
  {
    asm volatile("s_waitcnt vmcnt(0)" ::: "memory");
    asm volatile("s_barrier" ::: "memory");
    DSR(af0[0][0], aA0, 0);    DSR(af0[1][0], aA0, 2048);
    DSR(af0[0][1], aA1, 0);    DSR(af0[1][1], aA1, 2048);
    DSR(af1[0][0], aA0, 8192); DSR(af1[1][0], aA0, 10240);
    DSR(af1[0][1], aA1, 8192); DSR(af1[1][1], aA1, 10240);
    DSR(bf0[0][0], bA0, 0);    DSR(bf0[1][0], bA0, 2048);
    DSR(bf0[0][1], bA1, 0);    DSR(bf0[1][1], bA1, 2048);
    DSR(bf1[0][0], bA0, 8192); DSR(bf1[1][0], bA0, 10240);
    DSR(bf1[0][1], bA1, 8192); DSR(bf1[1][1], bA1, 10240);
    LGKM0;
#pragma unroll
    for (int kk = 0; kk < 2; ++kk)
#pragma unroll
      for (int i = 0; i < 2; ++i)
#pragma unroll
        for (int j = 0; j < 2; ++j)
          acc[0][0][i][j] = __builtin_amdgcn_mfma_f32_16x16x32_bf16(af0[i][kk], bf0[j][kk], acc[0][0][i][j], 0, 0, 0);
#pragma unroll
    for (int kk = 0; kk < 2; ++kk)
#pragma unroll
      for (int i = 0; i < 2; ++i)
#pragma unroll
        for (int j = 0; j < 2; ++j)
          acc[0][1][i][j] = __builtin_amdgcn_mfma_f32_16x16x32_bf16(af0[i][kk], bf1[j][kk], acc[0][1][i][j], 0, 0, 0);
#pragma unroll
    for (int kk = 0; kk < 2; ++kk)
#pragma unroll
      for (int i = 0; i < 2; ++i)
#pragma unroll
        for (int j = 0; j < 2; ++j)
          acc[1][0][i][j] = __builtin_amdgcn_mfma_f32_16x16x32_bf16(af1[i][kk], bf0[j][kk], acc[1][0][i][j], 0, 0, 0);
#pragma unroll
    for (int kk = 0; kk < 2; ++kk)
#pragma unroll
      for (int i = 0; i < 2; ++i)
#pragma unroll
        for (int j = 0; j < 2; ++j)
          acc[1][1][i][j] = __builtin_amdgcn_mfma_f32_16x16x32_bf16(af1[i][kk], bf1[j][kk], acc[1][1][i][j], 0, 0, 0);
    __builtin_amdgcn_sched_barrier(0);
  }

  // ---- epilogue
  float biasj[2][2];
#pragma unroll
  for (int qb = 0; qb < 2; ++qb)
#pragma unroll
    for (int j = 0; j < 2; ++j)
      biasj[qb][j] = bias[n0 + qb * 64 + wc * 32 + j * 16 + ln];

  if (z != 2) {
#pragma unroll
    for (int qa = 0; qa < 2; ++qa)
#pragma unroll
      for (int qb = 0; qb < 2; ++qb)
#pragma unroll
        for (int i = 0; i < 2; ++i)
#pragma unroll
          for (int j = 0; j < 2; ++j)
#pragma unroll
            for (int r = 0; r < 4; ++r) {
              int m = m0 + qa * 64 + wr * 32 + i * 16 + quad * 4 + r;
              int n = n0 + qb * 64 + wc * 32 + j * 16 + ln;
              int b_ = m >> 11, s = m & 2047;
              int h = n >> 6, d = n & 63;
              outb[(((size_t)b_ * Hh + h) * Ss + s) * HD + d] =
                  f2bf((acc[qa][qb][i][j][r] + biasj[qb][j]) * osc);
            }
  } else {
    // V: transpose to [b,h,d,s] through LDS (128x128 fits in one pass)
    __syncthreads();
#pragma unroll
    for (int qa = 0; qa < 2; ++qa)
#pragma unroll
      for (int qb = 0; qb < 2; ++qb)
#pragma unroll
        for (int i = 0; i < 2; ++i)
#pragma unroll
          for (int j = 0; j < 2; ++j)
#pragma unroll
            for (int r = 0; r < 4; ++r) {
              int nc = qb * 64 + wc * 32 + j * 16 + ln;
              int mr = qa * 64 + wr * 32 + i * 16 + quad * 4 + r;
              SMEM[nc * 136 + mr] = f2bf(acc[qa][qb][i][j][r] + biasj[qb][j]);
            }
    __syncthreads();
    int nr = t >> 1, mh = t & 1;
    int n = n0 + nr, h = n >> 6, d = n & 63;
    int b_ = m0 >> 11;
    int s0 = (m0 & 2047) + mh * 64;
#pragma unroll
    for (int q = 0; q < 8; ++q) {
      us8 vdat = *(const us8*)&SMEM[nr * 136 + mh * 64 + q * 8];
      *(us8*)&outb[(((size_t)b_ * Hh + h) * HD + d) * Ss + s0 + q * 8] = vdat;
    }
  }
}

// Flash attention, causal, S^T = K Q^T, max-free exp2 softmax.  (R15, verified)
// grid 512 (64 bh x 8 p), 512 thr / 8 waves, 2 blocks/CU. Block p owns
// q-tiles {15-p, p}; wave w owns 16-row strip w*16 of each. KVBLK=64,
// double-buffered K/V, two-barrier counted-vmcnt pipeline:
// per tile {stage(kt+1); vmcnt(2); bar; asm-LDS compute; bar}.
// LDS elems: Ks b0 [0,4096) b1 [4096,8192); Vt b0 [8192,12288) b1 [12288,16384);
// Ps [16384,25600). 51200 B total.
__global__ __launch_bounds__(512, 2) void flash_attn(const unsigned short* __restrict__ qkv,
                                                     float* __restrict__ out) {
  const int id = blockIdx.x;
  const int bh = id & 63;
  const int p = id >> 6;            // 0..7
  const int b_ = bh >> 4, h = bh & 15;

  const unsigned short* qb  = qkv + (size_t)bh * (Ss * HD);
  const unsigned short* kb  = qkv + (size_t)(64 + bh) * (Ss * HD);
  const unsigned short* vtb = qkv + (size_t)(128 + bh) * (Ss * HD);  // [d][s]

  __shared__ __bf16 LDS[25600];        // 51200 B (see header comment)

  const int t = threadIdx.x;
  const int wave = t >> 6, lane = t & 63, quad = lane >> 4, ln = lane & 15;
  const int uw = wave >> 2;            // 64-row subtile half within each q-tile

  const int r6 = t >> 3;
  const int cstage = ((t & 7) ^ (r6 & 7)) * 8;
  const int t8 = t * 8;

  const int qts[2] = { 15 - p, p };    // big q-tile first; small reuses staging
  const int KTB = 2 * qts[0] + 2;      // 64-col K/V tiles (block-uniform)
  const int su0 = 2 * qts[0] + uw;
  const int su1 = 2 * qts[1] + uw;
  const int qrow0 = qts[0] * 128 + wave * 16 + ln;
  const int qrow1 = qts[1] * 128 + wave * 16 + ln;

  int ka0 = ln * 128 + ((quad ^ (ln & 7)) * 16);
  int ka1 = ln * 128 + (((4 + quad) ^ (ln & 7)) * 16);
  const int pw = (16384 + (wave * 16 + ln) * 72 + quad * 4) * 2;
  const int pr = (16384 + (wave * 16 + ln) * 72 + quad * 8) * 2;

  bf16x8 qf[2][2];                     // [qt][ks] — loaded BEFORE any gl_lds16
#pragma unroll
  for (int qt = 0; qt < 2; ++qt)
#pragma unroll
    for (int ks = 0; ks < 2; ++ks)
      qf[qt][ks] = *(const bf16x8*)(qb + (size_t)(qts[qt] * 128 + wave * 16 + ln) * HD +
                                    ks * 32 + quad * 8);

  bf16x8 onef;
#pragma unroll
  for (int j = 0; j < 8; ++j) onef[j] = (__bf16)1.0f;

  f32x4 o[2][4] = {};                  // [qt][g]
  f32x4 l4[2] = {};                    // [qt]

  auto body = [&](int kt) {
    if (kt > su0) return;              // fully masked for this wave
    const bool a1 = (kt <= su1);
    const int k0 = kt * 64;
    f32x4 s0[4] = {}, s1[4] = {};
    bf16x8 kf[2][2];

    DSR(kf[0][0], ka0, 0);    DSR(kf[1][0], ka0, 2048);
    DSR(kf[0][1], ka1, 0);    DSR(kf[1][1], ka1, 2048);
    LGKM0;
#pragma unroll
    for (int ks = 0; ks < 2; ++ks) {
      s0[0] = __builtin_amdgcn_mfma_f32_16x16x32_bf16(kf[0][ks], qf[0][ks], s0[0], 0, 0, 0);
      s0[1] = __builtin_amdgcn_mfma_f32_16x16x32_bf16(kf[1][ks], qf[0][ks], s0[1], 0, 0, 0);
    }
    if (a1)
#pragma unroll
      for (int ks = 0; ks < 2; ++ks) {
        s1[0] = __builtin_amdgcn_mfma_f32_16x16x32_bf16(kf[0][ks], qf[1][ks], s1[0], 0, 0, 0);
        s1[1] = __builtin_amdgcn_mfma_f32_16x16x32_bf16(kf[1][ks], qf[1][ks], s1[1], 0, 0, 0);
      }
    DSR(kf[0][0], ka0, 4096); DSR(kf[1][0], ka0, 6144);
    DSR(kf[0][1], ka1, 4096); DSR(kf[1][1], ka1, 6144);
    LGKM0;
#pragma unroll
    for (int ks = 0; ks < 2; ++ks) {
      s0[2] = __builtin_amdgcn_mfma_f32_16x16x32_bf16(kf[0][ks], qf[0][ks], s0[2], 0, 0, 0);
      s0[3] = __builtin_amdgcn_mfma_f32_16x16x32_bf16(kf[1][ks], qf[0][ks], s0[3], 0, 0, 0);
    }
    if (a1)
#pragma unroll
      for (int ks = 0; ks < 2; ++ks) {
        s1[2] = __builtin_amdgcn_mfma_f32_16x16x32_bf16(kf[0][ks], qf[1][ks], s1[2], 0, 0, 0);
        s1[3] = __builtin_amdgcn_mfma_f32_16x16x32_bf16(kf[1][ks], qf[1][ks], s1[3], 0, 0, 0);
      }

    if (kt == su0) {
#pragma unroll
      for (int g = 0; g < 4; ++g)
#pragma unroll
        for (int r = 0; r < 4; ++r) {
          int kcol = k0 + g * 16 + quad * 4 + r;
          if (kcol > qrow0) s0[g][r] = -__builtin_inff();
        }
    }
    {
      bf16x4 pk;
      pk = bf16x4{ (__bf16)EXP2(s0[0][0]), (__bf16)EXP2(s0[0][1]), (__bf16)EXP2(s0[0][2]), (__bf16)EXP2(s0[0][3]) };
      DSW(pw, pk, 0);
      pk = bf16x4{ (__bf16)EXP2(s0[1][0]), (__bf16)EXP2(s0[1][1]), (__bf16)EXP2(s0[1][2]), (__bf16)EXP2(s0[1][3]) };
      DSW(pw, pk, 32);
      pk = bf16x4{ (__bf16)EXP2(s0[2][0]), (__bf16)EXP2(s0[2][1]), (__bf16)EXP2(s0[2][2]), (__bf16)EXP2(s0[2][3]) };
      DSW(pw, pk, 64);
      pk = bf16x4{ (__bf16)EXP2(s0[3][0]), (__bf16)EXP2(s0[3][1]), (__bf16)EXP2(s0[3][2]), (__bf16)EXP2(s0[3][3]) };
      DSW(pw, pk, 96);
    }
    bf16x8 pf0[2], pf1[2];
    DSR(pf0[0], pr, 0); DSR(pf0[1], pr, 64);
    LGKM0;

    if (a1) {
      if (kt == su1) {
#pragma unroll
        for (int g = 0; g < 4; ++g)
#pragma unroll
          for (int r = 0; r < 4; ++r) {
            int kcol = k0 + g * 16 + quad * 4 + r;
            if (kcol > qrow1) s1[g][r] = -__builtin_inff();
          }
      }
      bf16x4 pk;
      pk = bf16x4{ (__bf16)EXP2(s1[0][0]), (__bf16)EXP2(s1[0][1]), (__bf16)EXP2(s1[0][2]), (__bf16)EXP2(s1[0][3]) };
      DSW(pw, pk, 0);
      pk = bf16x4{ (__bf16)EXP2(s1[1][0]), (__bf16)EXP2(s1[1][1]), (__bf16)EXP2(s1[1][2]), (__bf16)EXP2(s1[1][3]) };
      DSW(pw, pk, 32);
      pk = bf16x4{ (__bf16)EXP2(s1[2][0]), (__bf16)EXP2(s1[2][1]), (__bf16)EXP2(s1[2][2]), (__bf16)EXP2(s1[2][3]) };
      DSW(pw, pk, 64);
      pk = bf16x4{ (__bf16)EXP2(s1[3][0]), (__bf16)EXP2(s1[3][1]), (__bf16)EXP2(s1[3][2]), (__bf16)EXP2(s1[3][3]) };
      DSW(pw, pk, 96);
      DSR(pf1[0], pr, 0); DSR(pf1[1], pr, 64);
      LGKM0;
    }

    l4[0] = __builtin_amdgcn_mfma_f32_16x16x32_bf16(pf0[0], onef, l4[0], 0, 0, 0);
    l4[0] = __builtin_amdgcn_mfma_f32_16x16x32_bf16(pf0[1], onef, l4[0], 0, 0, 0);
    if (a1) {
      l4[1] = __builtin_amdgcn_mfma_f32_16x16x32_bf16(pf1[0], onef, l4[1], 0, 0, 0);
      l4[1] = __builtin_amdgcn_mfma_f32_16x16x32_bf16(pf1[1], onef, l4[1], 0, 0, 0);
    }

    DSR(kf[0][0], ka0, 16384); DSR(kf[1][0], ka0, 18432);
    DSR(kf[0][1], ka1, 16384); DSR(kf[1][1], ka1, 18432);
    LGKM0;
#pragma unroll
    for (int ks = 0; ks < 2; ++ks) {
      o[0][0] = __builtin_amdgcn_mfma_f32_16x16x32_bf16(pf0[ks], kf[0][ks], o[0][0], 0, 0, 0);
      o[0][1] = __builtin_amdgcn_mfma_f32_16x16x32_bf16(pf0[ks], kf[1][ks], o[0][1], 0, 0, 0);
    }
    if (a1)
#pragma unroll
      for (int ks = 0; ks < 2; ++ks) {
        o[1][0] = __builtin_amdgcn_mfma_f32_16x16x32_bf16(pf1[ks], kf[0][ks], o[1][0], 0, 0, 0);
        o[1][1] = __builtin_amdgcn_mfma_f32_16x16x32_bf16(pf1[ks], kf[1][ks], o[1][1], 0, 0, 0);
      }
    DSR(kf[0][0], ka0, 20480); DSR(kf[1][0], ka0, 22528);
    DSR(kf[0][1], ka1, 20480); DSR(kf[1][1], ka1, 22528);
    LGKM0;
#pragma unroll
    for (int ks = 0; ks < 2; ++ks) {
      o[0][2] = __builtin_amdgcn_mfma_f32_16x16x32_bf16(pf0[ks], kf[0][ks], o[0][2], 0, 0, 0);
      o[0][3] = __builtin_amdgcn_mfma_f32_16x16x32_bf16(pf0[ks], kf[1][ks], o[0][3], 0, 0, 0);
    }
    if (a1)
#pragma unroll
      for (int ks = 0; ks < 2; ++ks) {
        o[1][2] = __builtin_amdgcn_mfma_f32_16x16x32_bf16(pf1[ks], kf[0][ks], o[1][2], 0, 0, 0);
        o[1][3] = __builtin_amdgcn_mfma_f32_16x16x32_bf16(pf1[ks], kf[1][ks], o[1][3], 0, 0, 0);
      }
  };

  // ---- prologue: stage tile 0 -> buf0
  gl_lds16(kb + r6 * HD + cstage,  &LDS[t8]);
  gl_lds16(vtb + r6 * Ss + cstage, &LDS[8192 + t8]);

#pragma unroll 1
  for (int kt = 0; kt < KTB - 1; ++kt) {
    const int sb = (kt & 1) ^ 1;       // stage buffer for tile kt+1
    gl_lds16(kb + (size_t)(kt + 1) * (64 * HD) + r6 * HD + cstage, &LDS[sb * 4096 + t8]);
    gl_lds16(vtb + (kt + 1) * 64 + r6 * Ss + cstage,               &LDS[8192 + sb * 4096 + t8]);
    asm volatile("s_waitcnt vmcnt(2)" ::: "memory");   // tile kt's K,V arrived
    asm volatile("s_barrier" ::: "memory");
    body(kt);
    asm volatile("s_barrier" ::: "memory");            // all reads done before next stage
    ka0 ^= 8192; ka1 ^= 8192;
  }
  asm volatile("s_waitcnt vmcnt(0)" ::: "memory");
  asm volatile("s_barrier" ::: "memory");
  body(KTB - 1);

  // epilogue: both q-tiles
#pragma unroll
  for (int qt = 0; qt < 2; ++qt) {
    float linv[4];
#pragma unroll
    for (int r = 0; r < 4; ++r) linv[r] = 1.0f / l4[qt][r];
#pragma unroll
    for (int g = 0; g < 4; ++g)
#pragma unroll
      for (int r = 0; r < 4; ++r) {
        int orow = qts[qt] * 128 + wave * 16 + quad * 4 + r;
        out[((size_t)b_ * Ss + orow) * Ee + h * HD + g * 16 + ln] = o[qt][g][r] * linv[r];
      }
  }
}

extern "C" void kernel_launch(void* const* d_in, const int* in_sizes, int n_in,
                              void* d_out, int out_size, void* d_ws, size_t ws_size,
                              hipStream_t stream) {
  const float* x  = (const float*)d_in[0];
  const float* Wq = (const float*)d_in[1];
  const float* bq = (const float*)d_in[2];
  const float* Wk = (const float*)d_in[3];
  const float* bk = (const float*)d_in[4];
  const float* Wv = (const float*)d_in[5];
  const float* bv = (const float*)d_in[6];
  float* out = (float*)d_out;

  unsigned short* ws  = (unsigned short*)d_ws;
  unsigned short* xb  = ws;                                   // 8388608
  unsigned short* wb  = ws + 8388608;                         // 3 * 1048576
  unsigned short* qkv = ws + 8388608 + 3 * 1048576;           // 3 * 8388608

  cvt_all<<<11264, 256, 0, stream>>>(x, Wq, Wk, Wv, xb, wb);
  qkv_gemm<<<dim3(64, 8, 3), 256, 0, stream>>>(xb, wb, bq, bk, bv, qkv);
  flash_attn<<<512, 512, 0, stream>>>(qkv, out);
}

// Round 11
// 193.907 us; speedup vs baseline: 1.0409x; 1.0049x over previous
//
#include <hip/hip_runtime.h>

// MaskedAttentionLayer B=4,S=2048,E=1024,H=16,HD=64; fp32 io, bf16 MFMA.
// R17: qkv_gemm tile body gets counted-lgkm overlap: 16 DSR issued in order
// (af0,bf0,af1,bf1); lgkmcnt(8) -> quadrant(0,0)'s 8 MFMA run while the
// last 8 reads drain; lgkmcnt(0) -> remaining 24 MFMA. Wait-count-only
// change (same loads, same order, same per-acc chains -> bit-identical).
// Everything else (R16 fused body, vmcnt(8) staging, grid, LDS) unchanged.
// flash_attn (R15 counted-vmcnt, verified) + cvt_all unchanged.

typedef __bf16 bf16x8 __attribute__((ext_vector_type(8)));
typedef __bf16 bf16x4 __attribute__((ext_vector_type(4)));
typedef float f32x4 __attribute__((ext_vector_type(4)));
typedef unsigned short us8 __attribute__((ext_vector_type(8)));
typedef unsigned short us4 __attribute__((ext_vector_type(4)));

#define Bb 4
#define Ss 2048
#define Ee 1024
#define Hh 16
#define HD 64

#if __has_builtin(__builtin_amdgcn_exp2f)
#define EXP2(x) __builtin_amdgcn_exp2f(x)
#else
#define EXP2(x) exp2f(x)
#endif

__device__ __forceinline__ unsigned short f2bf(float f) {
  union { float f; unsigned u; } v; v.f = f;
  unsigned u = v.u;
  u += 0x7fffu + ((u >> 16) & 1u);   // RNE
  return (unsigned short)(u >> 16);
}

__device__ __forceinline__ void gl_lds16(const void* g, void* l) {
  __builtin_amdgcn_global_load_lds((const __attribute__((address_space(1))) void*)g,
                                   (__attribute__((address_space(3))) void*)l, 16, 0, 0);
}

// asm LDS ops with compile-time byte offsets; opaque to compiler waitcnt logic.
#define DSR(d, a, o) asm volatile("ds_read_b128 %0, %1 offset:" #o : "=v"(d) : "v"(a))
#define DSW(a, d, o) asm volatile("ds_write_b64 %0, %1 offset:" #o :: "v"(a), "v"(d) : "memory")
#define LGKM0 asm volatile("s_waitcnt lgkmcnt(0)" ::: "memory"); __builtin_amdgcn_sched_barrier(0)
#define LGKM8 asm volatile("s_waitcnt lgkmcnt(8)" ::: "memory"); __builtin_amdgcn_sched_barrier(0)

// one kernel for all fp32->bf16 converts (x, Wq, Wk, Wv)
__global__ __launch_bounds__(256) void cvt_all(const float* __restrict__ x,
                                               const float* __restrict__ wq,
                                               const float* __restrict__ wk,
                                               const float* __restrict__ wv,
                                               unsigned short* __restrict__ xb,
                                               unsigned short* __restrict__ wb) {
  int i = blockIdx.x * 256 + threadIdx.x;   // float4 index, total 2883584
  const float* src; unsigned short* dst; int idx;
  if (i < 2097152)      { src = x;  dst = xb;                idx = i; }
  else if (i < 2359296) { src = wq; dst = wb;                idx = i - 2097152; }
  else if (i < 2621440) { src = wk; dst = wb + 1048576;      idx = i - 2359296; }
  else                  { src = wv; dst = wb + 2 * 1048576;  idx = i - 2621440; }
  float4 f = ((const float4*)src)[idx];
  us4 o = { f2bf(f.x), f2bf(f.y), f2bf(f.z), f2bf(f.w) };
  ((us4*)dst)[idx] = o;
}

// C[m,n] = sum_e X[m,e] W[n,e] + bias[n].
// 128x128 tile, BK=64, 256 threads = 4 waves, dispersed-quadrant map
// (wave (wr,wc) owns 32x32 of each 64x64 C-quadrant). LDS 64 KiB:
// 2 x (A[128][64] + B[128][64]) bf16, XOR chunk swizzle.
// R17: fused body with counted-lgkm overlap (see header). Grid (64,8,3) =
// 1536 blocks, 2 blocks/CU, 3 exact rounds.
// z=0 (Q): [b,h,s,d] scaled by 0.125*log2e.  z=1 (K): [b,h,s,d].  z=2 (V): [b,h,d,s].
__global__ __launch_bounds__(256, 2) void qkv_gemm(const unsigned short* __restrict__ xb,
                                                   const unsigned short* __restrict__ wb_all,
                                                   const float* __restrict__ bq,
                                                   const float* __restrict__ bk,
                                                   const float* __restrict__ bv,
                                                   unsigned short* __restrict__ qkv) {
  const int z = blockIdx.z;
  const unsigned short* wb = wb_all + (size_t)z * (Ee * Ee);
  const float* bias = (z == 0) ? bq : (z == 1) ? bk : bv;
  unsigned short* outb = qkv + (size_t)z * (Bb * Ss * Ee);
  const float osc = (z == 0) ? 0.180336880f : 1.0f;   // 0.125 * log2(e)

  __shared__ unsigned short SMEM[32768];   // 64 KiB: 2 x (A 8192 + B 8192 elems)

  const int t = threadIdx.x;
  const int wave = t >> 6, lane = t & 63, quad = lane >> 4, ln = lane & 15;
  const int wr = wave >> 1, wc = wave & 1;
  const int m0 = blockIdx.x * 128, n0 = blockIdx.y * 128;

  const int r32 = t >> 3;
  const int cs = ((t & 7) ^ (r32 & 7)) * 8;
  const int t8 = t * 8;
  const unsigned short* gA0 = xb + (size_t)(m0 + r32) * Ee + cs;       // A rows 0..63
  const unsigned short* gA1 = gA0 + 64 * Ee;                           // A rows 64..127
  const unsigned short* gB0 = wb + (size_t)(n0 + r32) * Ee + cs;       // B rows 0..63
  const unsigned short* gB1 = gB0 + 64 * Ee;                           // B rows 64..127

  const int swz0 = ((0 * 4 + quad) ^ (ln & 7)) * 16;
  const int swz1 = ((1 * 4 + quad) ^ (ln & 7)) * 16;
  int aA0 = (wr * 32 + ln) * 128 + swz0;
  int aA1 = (wr * 32 + ln) * 128 + swz1;
  int bA0 = 16384 + (wc * 32 + ln) * 128 + swz0;
  int bA1 = 16384 + (wc * 32 + ln) * 128 + swz1;

  f32x4 acc[2][2][2][2] = {};
  bf16x8 af0[2][2], af1[2][2], bf0[2][2], bf1[2][2];   // lo/hi A, lo/hi B

  // ---- prologue: stage tile 0 into buf0 (8 calls)
  gl_lds16(gA0,           &SMEM[t8]);
  gl_lds16(gA0 + 32 * Ee, &SMEM[t8 + 2048]);
  gl_lds16(gB0,           &SMEM[8192 + t8]);
  gl_lds16(gB0 + 32 * Ee, &SMEM[8192 + t8 + 2048]);
  gl_lds16(gB1,           &SMEM[12288 + t8]);
  gl_lds16(gB1 + 32 * Ee, &SMEM[12288 + t8 + 2048]);
  gl_lds16(gA1,           &SMEM[4096 + t8]);
  gl_lds16(gA1 + 32 * Ee, &SMEM[4096 + t8 + 2048]);

#pragma unroll 1
  for (int kt = 0; kt < 15; ++kt) {
    const int sbuf = ((kt & 1) << 14) ^ 16384;   // stage buffer (elems) for tile kt+1
    const int co = (kt + 1) * 64;                // next tile's K-column offset

    // ---- stage ALL of tile kt+1 (prev iteration's trailing barrier ensures
    // every wave finished reading this buffer)
    gl_lds16(gA0 + co,           &SMEM[sbuf + t8]);
    gl_lds16(gA0 + co + 32 * Ee, &SMEM[sbuf + t8 + 2048]);
    gl_lds16(gB0 + co,           &SMEM[sbuf + 8192 + t8]);
    gl_lds16(gB0 + co + 32 * Ee, &SMEM[sbuf + 8192 + t8 + 2048]);
    gl_lds16(gB1 + co,           &SMEM[sbuf + 12288 + t8]);
    gl_lds16(gB1 + co + 32 * Ee, &SMEM[sbuf + 12288 + t8 + 2048]);
    gl_lds16(gA1 + co,           &SMEM[sbuf + 4096 + t8]);
    gl_lds16(gA1 + co + 32 * Ee, &SMEM[sbuf + 4096 + t8 + 2048]);

    // tile kt's 8 loads arrived; kt+1's 8 stay in flight under the compute
    asm volatile("s_waitcnt vmcnt(8)" ::: "memory");
    asm volatile("s_barrier" ::: "memory");

    // ---- issue ALL 16 fragment reads; first 8 (af0,bf0) feed quadrant (0,0)
    DSR(af0[0][0], aA0, 0);    DSR(af0[1][0], aA0, 2048);
    DSR(af0[0][1], aA1, 0);    DSR(af0[1][1], aA1, 2048);
    DSR(bf0[0][0], bA0, 0);    DSR(bf0[1][0], bA0, 2048);
    DSR(bf0[0][1], bA1, 0);    DSR(bf0[1][1], bA1, 2048);
    DSR(af1[0][0], aA0, 8192); DSR(af1[1][0], aA0, 10240);
    DSR(af1[0][1], aA1, 8192); DSR(af1[1][1], aA1, 10240);
    DSR(bf1[0][0], bA0, 8192); DSR(bf1[1][0], bA0, 10240);
    DSR(bf1[0][1], bA1, 8192); DSR(bf1[1][1], bA1, 10240);
    LGKM8;                      // af0+bf0 ready; af1/bf1 still draining
    __builtin_amdgcn_s_setprio(1);
    // quadrant (0,0): af-lo x bf0 — overlaps the last 8 ds_reads
#pragma unroll
    for (int kk = 0; kk < 2; ++kk)
#pragma unroll
      for (int i = 0; i < 2; ++i)
#pragma unroll
        for (int j = 0; j < 2; ++j)
          acc[0][0][i][j] = __builtin_amdgcn_mfma_f32_16x16x32_bf16(af0[i][kk], bf0[j][kk], acc[0][0][i][j], 0, 0, 0);
    LGKM0;                      // all fragments ready
    // quadrant (0,1): af-lo x bf1
#pragma unroll
    for (int kk = 0; kk < 2; ++kk)
#pragma unroll
      for (int i = 0; i < 2; ++i)
#pragma unroll
        for (int j = 0; j < 2; ++j)
          acc[0][1][i][j] = __builtin_amdgcn_mfma_f32_16x16x32_bf16(af0[i][kk], bf1[j][kk], acc[0][1][i][j], 0, 0, 0);
    // quadrant (1,0): af-hi x bf0
#pragma unroll
    for (int kk = 0; kk < 2; ++kk)
#pragma unroll
      for (int i = 0; i < 2; ++i)
#pragma unroll
        for (int j = 0; j < 2; ++j)
          acc[1][0][i][j] = __builtin_amdgcn_mfma_f32_16x16x32_bf16(af1[i][kk], bf0[j][kk], acc[1][0][i][j], 0, 0, 0);
    // quadrant (1,1): af-hi x bf1
#pragma unroll
    for (int kk = 0; kk < 2; ++kk)
#pragma unroll
      for (int i = 0; i < 2; ++i)
#pragma unroll
        for (int j = 0; j < 2; ++j)
          acc[1][1][i][j] = __builtin_amdgcn_mfma_f32_16x16x32_bf16(af1[i][kk], bf1[j][kk], acc[1][1][i][j], 0, 0, 0);
    __builtin_amdgcn_s_setprio(0);
    __builtin_amdgcn_sched_barrier(0);
    asm volatile("s_barrier" ::: "memory");      // reads done before next stage

    aA0 ^= 32768; aA1 ^= 32768; bA0 ^= 32768; bA1 ^= 32768;
  }

  // ---- peeled tile 15: only place vmcnt drains to 0 (bases now at buf1)
  {
    asm volatile("s_waitcnt vmcnt(0)" ::: "memory");
    asm volatile("s_barrier" ::: "memory");
    DSR(af0[0][0], aA0, 0);    DSR(af0[1][0], aA0, 2048);
    DSR(af0[0][1], aA1, 0);    DSR(af0[1][1], aA1, 2048);
    DSR(bf0[0][0], bA0, 0);    DSR(bf0[1][0], bA0, 2048);
    DSR(bf0[0][1], bA1, 0);    DSR(bf0[1][1], bA1, 2048);
    DSR(af1[0][0], aA0, 8192); DSR(af1[1][0], aA0, 10240);
    DSR(af1[0][1], aA1, 8192); DSR(af1[1][1], aA1, 10240);
    DSR(bf1[0][0], bA0, 8192); DSR(bf1[1][0], bA0, 10240);
    DSR(bf1[0][1], bA1, 8192); DSR(bf1[1][1], bA1, 10240);
    LGKM8;
#pragma unroll
    for (int kk = 0; kk < 2; ++kk)
#pragma unroll
      for (int i = 0; i < 2; ++i)
#pragma unroll
        for (int j = 0; j < 2; ++j)
          acc[0][0][i][j] = __builtin_amdgcn_mfma_f32_16x16x32_bf16(af0[i][kk], bf0[j][kk], acc[0][0][i][j], 0, 0, 0);
    LGKM0;
#pragma unroll
    for (int kk = 0; kk < 2; ++kk)
#pragma unroll
      for (int i = 0; i < 2; ++i)
#pragma unroll
        for (int j = 0; j < 2; ++j)
          acc[0][1][i][j] = __builtin_amdgcn_mfma_f32_16x16x32_bf16(af0[i][kk], bf1[j][kk], acc[0][1][i][j], 0, 0, 0);
#pragma unroll
    for (int kk = 0; kk < 2; ++kk)
#pragma unroll
      for (int i = 0; i < 2; ++i)
#pragma unroll
        for (int j = 0; j < 2; ++j)
          acc[1][0][i][j] = __builtin_amdgcn_mfma_f32_16x16x32_bf16(af1[i][kk], bf0[j][kk], acc[1][0][i][j], 0, 0, 0);
#pragma unroll
    for (int kk = 0; kk < 2; ++kk)
#pragma unroll
      for (int i = 0; i < 2; ++i)
#pragma unroll
        for (int j = 0; j < 2; ++j)
          acc[1][1][i][j] = __builtin_amdgcn_mfma_f32_16x16x32_bf16(af1[i][kk], bf1[j][kk], acc[1][1][i][j], 0, 0, 0);
    __builtin_amdgcn_sched_barrier(0);
  }

  // ---- epilogue
  float biasj[2][2];
#pragma unroll
  for (int qb = 0; qb < 2; ++qb)
#pragma unroll
    for (int j = 0; j < 2; ++j)
      biasj[qb][j] = bias[n0 + qb * 64 + wc * 32 + j * 16 + ln];

  if (z != 2) {
#pragma unroll
    for (int qa = 0; qa < 2; ++qa)
#pragma unroll
      for (int qb = 0; qb < 2; ++qb)
#pragma unroll
        for (int i = 0; i < 2; ++i)
#pragma unroll
          for (int j = 0; j < 2; ++j)
#pragma unroll
            for (int r = 0; r < 4; ++r) {
              int m = m0 + qa * 64 + wr * 32 + i * 16 + quad * 4 + r;
              int n = n0 + qb * 64 + wc * 32 + j * 16 + ln;
              int b_ = m >> 11, s = m & 2047;
              int h = n >> 6, d = n & 63;
              outb[(((size_t)b_ * Hh + h) * Ss + s) * HD + d] =
                  f2bf((acc[qa][qb][i][j][r] + biasj[qb][j]) * osc);
            }
  } else {
    // V: transpose to [b,h,d,s] through LDS (128x128 fits in one pass)
    __syncthreads();
#pragma unroll
    for (int qa = 0; qa < 2; ++qa)
#pragma unroll
      for (int qb = 0; qb < 2; ++qb)
#pragma unroll
        for (int i = 0; i < 2; ++i)
#pragma unroll
          for (int j = 0; j < 2; ++j)
#pragma unroll
            for (int r = 0; r < 4; ++r) {
              int nc = qb * 64 + wc * 32 + j * 16 + ln;
              int mr = qa * 64 + wr * 32 + i * 16 + quad * 4 + r;
              SMEM[nc * 136 + mr] = f2bf(acc[qa][qb][i][j][r] + biasj[qb][j]);
            }
    __syncthreads();
    int nr = t >> 1, mh = t & 1;
    int n = n0 + nr, h = n >> 6, d = n & 63;
    int b_ = m0 >> 11;
    int s0 = (m0 & 2047) + mh * 64;
#pragma unroll
    for (int q = 0; q < 8; ++q) {
      us8 vdat = *(const us8*)&SMEM[nr * 136 + mh * 64 + q * 8];
      *(us8*)&outb[(((size_t)b_ * Hh + h) * HD + d) * Ss + s0 + q * 8] = vdat;
    }
  }
}

// Flash attention, causal, S^T = K Q^T, max-free exp2 softmax.  (R15, verified)
// grid 512 (64 bh x 8 p), 512 thr / 8 waves, 2 blocks/CU. Block p owns
// q-tiles {15-p, p}; wave w owns 16-row strip w*16 of each. KVBLK=64,
// double-buffered K/V, two-barrier counted-vmcnt pipeline:
// per tile {stage(kt+1); vmcnt(2); bar; asm-LDS compute; bar}.
// LDS elems: Ks b0 [0,4096) b1 [4096,8192); Vt b0 [8192,12288) b1 [12288,16384);
// Ps [16384,25600). 51200 B total.
__global__ __launch_bounds__(512, 2) void flash_attn(const unsigned short* __restrict__ qkv,
                                                     float* __restrict__ out) {
  const int id = blockIdx.x;
  const int bh = id & 63;
  const int p = id >> 6;            // 0..7
  const int b_ = bh >> 4, h = bh & 15;

  const unsigned short* qb  = qkv + (size_t)bh * (Ss * HD);
  const unsigned short* kb  = qkv + (size_t)(64 + bh) * (Ss * HD);
  const unsigned short* vtb = qkv + (size_t)(128 + bh) * (Ss * HD);  // [d][s]

  __shared__ __bf16 LDS[25600];        // 51200 B (see header comment)

  const int t = threadIdx.x;
  const int wave = t >> 6, lane = t & 63, quad = lane >> 4, ln = lane & 15;
  const int uw = wave >> 2;            // 64-row subtile half within each q-tile

  const int r6 = t >> 3;
  const int cstage = ((t & 7) ^ (r6 & 7)) * 8;
  const int t8 = t * 8;

  const int qts[2] = { 15 - p, p };    // big q-tile first; small reuses staging
  const int KTB = 2 * qts[0] + 2;      // 64-col K/V tiles (block-uniform)
  const int su0 = 2 * qts[0] + uw;
  const int su1 = 2 * qts[1] + uw;
  const int qrow0 = qts[0] * 128 + wave * 16 + ln;
  const int qrow1 = qts[1] * 128 + wave * 16 + ln;

  int ka0 = ln * 128 + ((quad ^ (ln & 7)) * 16);
  int ka1 = ln * 128 + (((4 + quad) ^ (ln & 7)) * 16);
  const int pw = (16384 + (wave * 16 + ln) * 72 + quad * 4) * 2;
  const int pr = (16384 + (wave * 16 + ln) * 72 + quad * 8) * 2;

  bf16x8 qf[2][2];                     // [qt][ks] — loaded BEFORE any gl_lds16
#pragma unroll
  for (int qt = 0; qt < 2; ++qt)
#pragma unroll
    for (int ks = 0; ks < 2; ++ks)
      qf[qt][ks] = *(const bf16x8*)(qb + (size_t)(qts[qt] * 128 + wave * 16 + ln) * HD +
                                    ks * 32 + quad * 8);

  bf16x8 onef;
#pragma unroll
  for (int j = 0; j < 8; ++j) onef[j] = (__bf16)1.0f;

  f32x4 o[2][4] = {};                  // [qt][g]
  f32x4 l4[2] = {};                    // [qt]

  auto body = [&](int kt) {
    if (kt > su0) return;              // fully masked for this wave
    const bool a1 = (kt <= su1);
    const int k0 = kt * 64;
    f32x4 s0[4] = {}, s1[4] = {};
    bf16x8 kf[2][2];

    DSR(kf[0][0], ka0, 0);    DSR(kf[1][0], ka0, 2048);
    DSR(kf[0][1], ka1, 0);    DSR(kf[1][1], ka1, 2048);
    LGKM0;
#pragma unroll
    for (int ks = 0; ks < 2; ++ks) {
      s0[0] = __builtin_amdgcn_mfma_f32_16x16x32_bf16(kf[0][ks], qf[0][ks], s0[0], 0, 0, 0);
      s0[1] = __builtin_amdgcn_mfma_f32_16x16x32_bf16(kf[1][ks], qf[0][ks], s0[1], 0, 0, 0);
    }
    if (a1)
#pragma unroll
      for (int ks = 0; ks < 2; ++ks) {
        s1[0] = __builtin_amdgcn_mfma_f32_16x16x32_bf16(kf[0][ks], qf[1][ks], s1[0], 0, 0, 0);
        s1[1] = __builtin_amdgcn_mfma_f32_16x16x32_bf16(kf[1][ks], qf[1][ks], s1[1], 0, 0, 0);
      }
    DSR(kf[0][0], ka0, 4096); DSR(kf[1][0], ka0, 6144);
    DSR(kf[0][1], ka1, 4096); DSR(kf[1][1], ka1, 6144);
    LGKM0;
#pragma unroll
    for (int ks = 0; ks < 2; ++ks) {
      s0[2] = __builtin_amdgcn_mfma_f32_16x16x32_bf16(kf[0][ks], qf[0][ks], s0[2], 0, 0, 0);
      s0[3] = __builtin_amdgcn_mfma_f32_16x16x32_bf16(kf[1][ks], qf[0][ks], s0[3], 0, 0, 0);
    }
    if (a1)
#pragma unroll
      for (int ks = 0; ks < 2; ++ks) {
        s1[2] = __builtin_amdgcn_mfma_f32_16x16x32_bf16(kf[0][ks], qf[1][ks], s1[2], 0, 0, 0);
        s1[3] = __builtin_amdgcn_mfma_f32_16x16x32_bf16(kf[1][ks], qf[1][ks], s1[3], 0, 0, 0);
      }

    if (kt == su0) {
#pragma unroll
      for (int g = 0; g < 4; ++g)
#pragma unroll
        for (int r = 0; r < 4; ++r) {
          int kcol = k0 + g * 16 + quad * 4 + r;
          if (kcol > qrow0) s0[g][r] = -__builtin_inff();
        }
    }
    {
      bf16x4 pk;
      pk = bf16x4{ (__bf16)EXP2(s0[0][0]), (__bf16)EXP2(s0[0][1]), (__bf16)EXP2(s0[0][2]), (__bf16)EXP2(s0[0][3]) };
      DSW(pw, pk, 0);
      pk = bf16x4{ (__bf16)EXP2(s0[1][0]), (__bf16)EXP2(s0[1][1]), (__bf16)EXP2(s0[1][2]), (__bf16)EXP2(s0[1][3]) };
      DSW(pw, pk, 32);
      pk = bf16x4{ (__bf16)EXP2(s0[2][0]), (__bf16)EXP2(s0[2][1]), (__bf16)EXP2(s0[2][2]), (__bf16)EXP2(s0[2][3]) };
      DSW(pw, pk, 64);
      pk = bf16x4{ (__bf16)EXP2(s0[3][0]), (__bf16)EXP2(s0[3][1]), (__bf16)EXP2(s0[3][2]), (__bf16)EXP2(s0[3][3]) };
      DSW(pw, pk, 96);
    }
    bf16x8 pf0[2], pf1[2];
    DSR(pf0[0], pr, 0); DSR(pf0[1], pr, 64);
    LGKM0;

    if (a1) {
      if (kt == su1) {
#pragma unroll
        for (int g = 0; g < 4; ++g)
#pragma unroll
          for (int r = 0; r < 4; ++r) {
            int kcol = k0 + g * 16 + quad * 4 + r;
            if (kcol > qrow1) s1[g][r] = -__builtin_inff();
          }
      }
      bf16x4 pk;
      pk = bf16x4{ (__bf16)EXP2(s1[0][0]), (__bf16)EXP2(s1[0][1]), (__bf16)EXP2(s1[0][2]), (__bf16)EXP2(s1[0][3]) };
      DSW(pw, pk, 0);
      pk = bf16x4{ (__bf16)EXP2(s1[1][0]), (__bf16)EXP2(s1[1][1]), (__bf16)EXP2(s1[1][2]), (__bf16)EXP2(s1[1][3]) };
      DSW(pw, pk, 32);
      pk = bf16x4{ (__bf16)EXP2(s1[2][0]), (__bf16)EXP2(s1[2][1]), (__bf16)EXP2(s1[2][2]), (__bf16)EXP2(s1[2][3]) };
      DSW(pw, pk, 64);
      pk = bf16x4{ (__bf16)EXP2(s1[3][0]), (__bf16)EXP2(s1[3][1]), (__bf16)EXP2(s1[3][2]), (__bf16)EXP2(s1[3][3]) };
      DSW(pw, pk, 96);
      DSR(pf1[0], pr, 0); DSR(pf1[1], pr, 64);
      LGKM0;
    }

    l4[0] = __builtin_amdgcn_mfma_f32_16x16x32_bf16(pf0[0], onef, l4[0], 0, 0, 0);
    l4[0] = __builtin_amdgcn_mfma_f32_16x16x32_bf16(pf0[1], onef, l4[0], 0, 0, 0);
    if (a1) {
      l4[1] = __builtin_amdgcn_mfma_f32_16x16x32_bf16(pf1[0], onef, l4[1], 0, 0, 0);
      l4[1] = __builtin_amdgcn_mfma_f32_16x16x32_bf16(pf1[1], onef, l4[1], 0, 0, 0);
    }

    DSR(kf[0][0], ka0, 16384); DSR(kf[1][0], ka0, 18432);
    DSR(kf[0][1], ka1, 16384); DSR(kf[1][1], ka1, 18432);
    LGKM0;
#pragma unroll
    for (int ks = 0; ks < 2; ++ks) {
      o[0][0] = __builtin_amdgcn_mfma_f32_16x16x32_bf16(pf0[ks], kf[0][ks], o[0][0], 0, 0, 0);
      o[0][1] = __builtin_amdgcn_mfma_f32_16x16x32_bf16(pf0[ks], kf[1][ks], o[0][1], 0, 0, 0);
    }
    if (a1)
#pragma unroll
      for (int ks = 0; ks < 2; ++ks) {
        o[1][0] = __builtin_amdgcn_mfma_f32_16x16x32_bf16(pf1[ks], kf[0][ks], o[1][0], 0, 0, 0);
        o[1][1] = __builtin_amdgcn_mfma_f32_16x16x32_bf16(pf1[ks], kf[1][ks], o[1][1], 0, 0, 0);
      }
    DSR(kf[0][0], ka0, 20480); DSR(kf[1][0], ka0, 22528);
    DSR(kf[0][1], ka1, 20480); DSR(kf[1][1], ka1, 22528);
    LGKM0;
#pragma unroll
    for (int ks = 0; ks < 2; ++ks) {
      o[0][2] = __builtin_amdgcn_mfma_f32_16x16x32_bf16(pf0[ks], kf[0][ks], o[0][2], 0, 0, 0);
      o[0][3] = __builtin_amdgcn_mfma_f32_16x16x32_bf16(pf0[ks], kf[1][ks], o[0][3], 0, 0, 0);
    }
    if (a1)
#pragma unroll
      for (int ks = 0; ks < 2; ++ks) {
        o[1][2] = __builtin_amdgcn_mfma_f32_16x16x32_bf16(pf1[ks], kf[0][ks], o[1][2], 0, 0, 0);
        o[1][3] = __builtin_amdgcn_mfma_f32_16x16x32_bf16(pf1[ks], kf[1][ks], o[1][3], 0, 0, 0);
      }
  };

  // ---- prologue: stage tile 0 -> buf0
  gl_lds16(kb + r6 * HD + cstage,  &LDS[t8]);
  gl_lds16(vtb + r6 * Ss + cstage, &LDS[8192 + t8]);

#pragma unroll 1
  for (int kt = 0; kt < KTB - 1; ++kt) {
    const int sb = (kt & 1) ^ 1;       // stage buffer for tile kt+1
    gl_lds16(kb + (size_t)(kt + 1) * (64 * HD) + r6 * HD + cstage, &LDS[sb * 4096 + t8]);
    gl_lds16(vtb + (kt + 1) * 64 + r6 * Ss + cstage,               &LDS[8192 + sb * 4096 + t8]);
    asm volatile("s_waitcnt vmcnt(2)" ::: "memory");   // tile kt's K,V arrived
    asm volatile("s_barrier" ::: "memory");
    body(kt);
    asm volatile("s_barrier" ::: "memory");            // all reads done before next stage
    ka0 ^= 8192; ka1 ^= 8192;
  }
  asm volatile("s_waitcnt vmcnt(0)" ::: "memory");
  asm volatile("s_barrier" ::: "memory");
  body(KTB - 1);

  // epilogue: both q-tiles
#pragma unroll
  for (int qt = 0; qt < 2; ++qt) {
    float linv[4];
#pragma unroll
    for (int r = 0; r < 4; ++r) linv[r] = 1.0f / l4[qt][r];
#pragma unroll
    for (int g = 0; g < 4; ++g)
#pragma unroll
      for (int r = 0; r < 4; ++r) {
        int orow = qts[qt] * 128 + wave * 16 + quad * 4 + r;
        out[((size_t)b_ * Ss + orow) * Ee + h * HD + g * 16 + ln] = o[qt][g][r] * linv[r];
      }
  }
}

extern "C" void kernel_launch(void* const* d_in, const int* in_sizes, int n_in,
                              void* d_out, int out_size, void* d_ws, size_t ws_size,
                              hipStream_t stream) {
  const float* x  = (const float*)d_in[0];
  const float* Wq = (const float*)d_in[1];
  const float* bq = (const float*)d_in[2];
  const float* Wk = (const float*)d_in[3];
  const float* bk = (const float*)d_in[4];
  const float* Wv = (const float*)d_in[5];
  const float* bv = (const float*)d_in[6];
  float* out = (float*)d_out;

  unsigned short* ws  = (unsigned short*)d_ws;
  unsigned short* xb  = ws;                                   // 8388608
  unsigned short* wb  = ws + 8388608;                         // 3 * 1048576
  unsigned short* qkv = ws + 8388608 + 3 * 1048576;           // 3 * 8388608

  cvt_all<<<11264, 256, 0, stream>>>(x, Wq, Wk, Wv, xb, wb);
  qkv_gemm<<<dim3(64, 8, 3), 256, 0, stream>>>(xb, wb, bq, bk, bv, qkv);
  flash_attn<<<512, 512, 0, stream>>>(qkv, out);
}